// Round 7
// baseline (708.078 us; speedup 1.0000x reference)
//
#include <hip/hip_runtime.h>

// GCN forward + NCut loss on MI355X.
// R7: untiled CSR (tiling falsified in R6); fused 8B edge records E={colB,w}
//     (kills scatter write amplification: one 8B store/edge, 3.2MB open-line set);
//     CSR-style k_loss (Y[r] loaded once per node, streams E).
// loss = 16 - sum_e w_e * sum_j Y[row,j]*Y[col,j]/Gamma[j]

constexpr int NN = 50000;
constexpr int NE = 1600000;
constexpr int F0 = 512;
constexpr int F1 = 256;
constexpr int G  = 16;
constexpr int NB = (NN + 1023) / 1024;   // 49 scan blocks

typedef short  s16x8 __attribute__((ext_vector_type(8)));
typedef float  f32x4 __attribute__((ext_vector_type(4)));
typedef float  f32x2 __attribute__((ext_vector_type(2)));
typedef int    i32x4 __attribute__((ext_vector_type(4)));
typedef float  fv4   __attribute__((ext_vector_type(4)));

static __device__ __forceinline__ unsigned short f2bf(float f) {
    union { float f; unsigned u; } v; v.f = f;
    unsigned r = (v.u + 0x7FFFu + ((v.u >> 16) & 1u)) >> 16;   // RNE
    return (unsigned short)r;
}
static __device__ __forceinline__ float bf2f(unsigned short u) {
    union { unsigned u; float f; } v; v.u = (unsigned)u << 16;
    return v.f;
}

// ---------------- CSR build ----------------
__global__ __launch_bounds__(256) void k_hist(const int* __restrict__ row, int* __restrict__ counts) {
    int idx = blockIdx.x * 256 + threadIdx.x;
    if (idx < NE / 4) {
        i32x4 r = __builtin_nontemporal_load(&((const i32x4*)row)[idx]);
        atomicAdd(&counts[r.x], 1);
        atomicAdd(&counts[r.y], 1);
        atomicAdd(&counts[r.z], 1);
        atomicAdd(&counts[r.w], 1);
    }
}

__global__ __launch_bounds__(1024) void k_scan1(const int* __restrict__ counts, int* __restrict__ bsum) {
    __shared__ int sh[1024];
    const int tid = threadIdx.x;
    int i = blockIdx.x * 1024 + tid;
    sh[tid] = (i < NN) ? counts[i] : 0;
    __syncthreads();
    for (int off = 512; off > 0; off >>= 1) {
        if (tid < off) sh[tid] += sh[tid + off];
        __syncthreads();
    }
    if (tid == 0) bsum[blockIdx.x] = sh[0];
}

__global__ void k_scan2(const int* __restrict__ bsum, int* __restrict__ bofs, int* __restrict__ rowptr) {
    const int tid = threadIdx.x;   // 64 threads, NB=49
    int orig = (tid < NB) ? bsum[tid] : 0;
    int v = orig;
    for (int off = 1; off < 64; off <<= 1) {
        int t = __shfl_up(v, off, 64);
        if (tid >= off) v += t;
    }
    if (tid < NB) bofs[tid] = v - orig;   // exclusive
    if (tid == 63) rowptr[NN] = v;
}

__global__ __launch_bounds__(1024) void k_scan3(const int* __restrict__ counts, const int* __restrict__ bofs,
                                                int* __restrict__ rowptr, int* __restrict__ cursor) {
    __shared__ int sh[1024];
    const int tid = threadIdx.x;
    int i = blockIdx.x * 1024 + tid;
    int orig = (i < NN) ? counts[i] : 0;
    sh[tid] = orig;
    __syncthreads();
    for (int off = 1; off < 1024; off <<= 1) {
        int t = (tid >= off) ? sh[tid - off] : 0;
        __syncthreads();
        sh[tid] += t;
        __syncthreads();
    }
    int ex = sh[tid] - orig + bofs[blockIdx.x];
    if (i < NN) { rowptr[i] = ex; cursor[i] = ex; }
}

// fused edge record: {col byte-offset into XW (c<<8), float weight bits}
__global__ __launch_bounds__(256) void k_scatter(const int* __restrict__ row, const int* __restrict__ col,
                                                 const float* __restrict__ ev, int* __restrict__ cursor,
                                                 int2* __restrict__ E) {
    int idx = blockIdx.x * 256 + threadIdx.x;
    if (idx < NE / 4) {
        i32x4 r = __builtin_nontemporal_load(&((const i32x4*)row)[idx]);
        i32x4 c = __builtin_nontemporal_load(&((const i32x4*)col)[idx]);
        fv4   w = __builtin_nontemporal_load(&((const fv4*)ev)[idx]);
        int p;
        p = atomicAdd(&cursor[r.x], 1); E[p] = make_int2(c.x << 8, __float_as_int(w.x));
        p = atomicAdd(&cursor[r.y], 1); E[p] = make_int2(c.y << 8, __float_as_int(w.y));
        p = atomicAdd(&cursor[r.z], 1); E[p] = make_int2(c.z << 8, __float_as_int(w.z));
        p = atomicAdd(&cursor[r.w], 1); E[p] = make_int2(c.w << 8, __float_as_int(w.w));
    }
}

// ---------------- W1 pre-cast+transpose ----------------
__global__ __launch_bounds__(256) void k_castW1(const float* __restrict__ W1, unsigned short* __restrict__ W1t) {
    int idx = blockIdx.x * 256 + threadIdx.x;
    if (idx < F0 * F1) {
        int k = idx >> 8, n = idx & 255;
        W1t[n * F0 + k] = f2bf(W1[idx]);
    }
}

// ---------------- GEMM1 (bf16 MFMA): XW = fp8(H @ W1) ----------------
__global__ __launch_bounds__(256) void k_gemm1(const float* __restrict__ H, const unsigned short* __restrict__ W1t,
                                               unsigned char* __restrict__ XW) {
    __shared__ unsigned short As[128][72];
    __shared__ unsigned short Bs[128][72];
    const int tid  = threadIdx.x;
    const int lane = tid & 63;
    const int wave = tid >> 6;
    const int bm = blockIdx.x * 128;
    const int bn = blockIdx.y * 128;
    const int m_off = (wave & 1) * 64;
    const int n_off = (wave >> 1) * 64;
    const int l15  = lane & 15;
    const int quad = lane >> 4;

    f32x4 acc[4][4];
#pragma unroll
    for (int i = 0; i < 4; ++i)
#pragma unroll
        for (int j = 0; j < 4; ++j) acc[i][j] = (f32x4)0.f;

    const int arow = tid >> 4;
    const int akq  = tid & 15;
    const int brow = tid >> 3;
    const int bkq  = tid & 7;

    for (int k0 = 0; k0 < F0; k0 += 64) {
        __syncthreads();
#pragma unroll
        for (int p = 0; p < 8; ++p) {
            int r = p * 16 + arow;
            int gr = bm + r;
            float4 a4 = make_float4(0.f, 0.f, 0.f, 0.f);
            if (gr < NN) a4 = *(const float4*)&H[(size_t)gr * F0 + k0 + akq * 4];
            unsigned short* dst = &As[r][akq * 4];
            dst[0] = f2bf(a4.x); dst[1] = f2bf(a4.y); dst[2] = f2bf(a4.z); dst[3] = f2bf(a4.w);
        }
#pragma unroll
        for (int p = 0; p < 4; ++p) {
            int n = p * 32 + brow;
            uint4 b8 = *(const uint4*)&W1t[(bn + n) * F0 + k0 + bkq * 8];
            *(uint4*)&Bs[n][bkq * 8] = b8;
        }
        __syncthreads();
#pragma unroll
        for (int kk = 0; kk < 64; kk += 32) {
            s16x8 af[4], bfr[4];
#pragma unroll
            for (int mi = 0; mi < 4; ++mi)
                af[mi] = *(const s16x8*)&As[m_off + mi * 16 + l15][kk + quad * 8];
#pragma unroll
            for (int ni = 0; ni < 4; ++ni)
                bfr[ni] = *(const s16x8*)&Bs[n_off + ni * 16 + l15][kk + quad * 8];
#pragma unroll
            for (int mi = 0; mi < 4; ++mi)
#pragma unroll
                for (int ni = 0; ni < 4; ++ni)
                    acc[mi][ni] = __builtin_amdgcn_mfma_f32_16x16x32_bf16(af[mi], bfr[ni], acc[mi][ni], 0, 0, 0);
        }
    }
#pragma unroll
    for (int mi = 0; mi < 4; ++mi) {
        int r0 = bm + m_off + mi * 16 + quad * 4;
#pragma unroll
        for (int reg = 0; reg < 4; ++reg) {
            int gr = r0 + reg;
            if (gr < NN) {
                unsigned char* orow = &XW[(size_t)gr * F1 + bn + n_off];
#pragma unroll
                for (int ni = 0; ni < 4; ++ni) {
                    int pk = __builtin_amdgcn_cvt_pk_fp8_f32(acc[mi][ni][reg], 0.f, 0, false);
                    orow[ni * 16 + l15] = (unsigned char)(pk & 0xff);
                }
            }
        }
    }
}

// ---------------- SPMM1 + bias + relu + fused GEMM2 (fp8 gather) ----------------
__global__ __launch_bounds__(256) void k_spmm1(const unsigned char* __restrict__ XW, const int* __restrict__ rowptr,
                                               const int2* __restrict__ E,
                                               const float* __restrict__ b1, const float* __restrict__ W2,
                                               unsigned short* __restrict__ Z, float* __restrict__ Dv) {
    __shared__ float W2T[G * F1];
    const int tid = threadIdx.x;
#pragma unroll
    for (int it = 0; it < 16; ++it)
        W2T[it * 256 + tid] = W2[tid * 16 + it];   // conflict-free writes
    __syncthreads();
    const int lane = tid & 63;
    const int lane4 = lane * 4;
    const int n = blockIdx.x * 4 + (tid >> 6);
    const int s = __builtin_amdgcn_readfirstlane(rowptr[n]);
    const int e = __builtin_amdgcn_readfirstlane(rowptr[n + 1]);

    float4 acc = make_float4(0.f, 0.f, 0.f, 0.f);
    float wsum = 0.f;
    int i = s;
    for (; i + 8 <= e; i += 8) {
        int of[8]; float w[8];
#pragma unroll
        for (int k = 0; k < 8; ++k) {
            int2 ed = E[i + k];
            of[k] = ed.x; w[k] = __int_as_float(ed.y);
        }
        unsigned gg[8];
#pragma unroll
        for (int k = 0; k < 8; ++k) gg[k] = *(const unsigned*)(XW + of[k] + lane4);
#pragma unroll
        for (int k = 0; k < 8; ++k) {
            f32x2 lo = __builtin_amdgcn_cvt_pk_f32_fp8(gg[k], false);
            f32x2 hi = __builtin_amdgcn_cvt_pk_f32_fp8(gg[k], true);
            acc.x = fmaf(w[k], lo.x, acc.x); acc.y = fmaf(w[k], lo.y, acc.y);
            acc.z = fmaf(w[k], hi.x, acc.z); acc.w = fmaf(w[k], hi.y, acc.w);
            wsum += w[k];
        }
    }
    for (; i < e; i += 4) {
        int of[4]; float w[4];
#pragma unroll
        for (int k = 0; k < 4; ++k) {
            int idx = i + k;
            bool ok = idx < e;
            int2 ed = E[ok ? idx : s];
            of[k] = ed.x; w[k] = ok ? __int_as_float(ed.y) : 0.f;
        }
        unsigned gg[4];
#pragma unroll
        for (int k = 0; k < 4; ++k) gg[k] = *(const unsigned*)(XW + of[k] + lane4);
#pragma unroll
        for (int k = 0; k < 4; ++k) {
            f32x2 lo = __builtin_amdgcn_cvt_pk_f32_fp8(gg[k], false);
            f32x2 hi = __builtin_amdgcn_cvt_pk_f32_fp8(gg[k], true);
            acc.x = fmaf(w[k], lo.x, acc.x); acc.y = fmaf(w[k], lo.y, acc.y);
            acc.z = fmaf(w[k], hi.x, acc.z); acc.w = fmaf(w[k], hi.y, acc.w);
            wsum += w[k];
        }
    }
    if (lane == 0) Dv[n] = wsum;

    float4 bb = *(const float4*)&b1[lane * 4];
    float4 h;
    h.x = fmaxf(acc.x + bb.x, 0.f);
    h.y = fmaxf(acc.y + bb.y, 0.f);
    h.z = fmaxf(acc.z + bb.z, 0.f);
    h.w = fmaxf(acc.w + bb.w, 0.f);

    float p[G];
#pragma unroll
    for (int j = 0; j < G; ++j) {
        float4 w4 = *(const float4*)&W2T[j * F1 + lane * 4];
        p[j] = h.x * w4.x + h.y * w4.y + h.z * w4.z + h.w * w4.w;
    }
#pragma unroll
    for (int off = 1; off < 64; off <<= 1) {
#pragma unroll
        for (int j = 0; j < G; ++j) p[j] += __shfl_xor(p[j], off, 64);
    }
    if (lane == 0) {
        unsigned zp[8];
#pragma unroll
        for (int j = 0; j < 8; ++j)
            zp[j] = (unsigned)f2bf(p[2 * j]) | ((unsigned)f2bf(p[2 * j + 1]) << 16);
        uint4* zo = (uint4*)&Z[n * G];
        zo[0] = make_uint4(zp[0], zp[1], zp[2], zp[3]);
        zo[1] = make_uint4(zp[4], zp[5], zp[6], zp[7]);
    }
}

// ---------------- SPMM2 + head + softmax + Gamma: 8 edges per gather instr ----------------
__global__ __launch_bounds__(256) void k_head(const unsigned short* __restrict__ Zb, const int* __restrict__ rowptr,
                                              const int2* __restrict__ E,
                                              const float* __restrict__ b2, const float* __restrict__ Wl,
                                              const float* __restrict__ bl, const float* __restrict__ Dv,
                                              unsigned short* __restrict__ Yb, float* __restrict__ GammaP) {
    __shared__ float WlS[G * G];
    __shared__ float gsh[G];
    const int tid = threadIdx.x;
    if (tid < G * G) WlS[tid] = Wl[tid];
    if (tid < G) gsh[tid] = 0.f;
    __syncthreads();
    const int lane = tid & 63;
    const int g = lane >> 3;      // edge slot 0..7
    const int d = lane & 7;       // dword in Z row
    const int n = blockIdx.x * 4 + (tid >> 6);
    const int s = __builtin_amdgcn_readfirstlane(rowptr[n]);
    const int e = __builtin_amdgcn_readfirstlane(rowptr[n + 1]);
    const char* Zc = (const char*)Zb;

    float a0 = 0.f, a1 = 0.f;
    for (int base = s; base < e; base += 16) {
        int i0 = base + g;
        int i1 = base + 8 + g;
        int2 e0 = E[(i0 < e) ? i0 : s];
        int2 e1 = E[(i1 < e) ? i1 : s];
        float w0 = (i0 < e) ? __int_as_float(e0.y) : 0.f;
        float w1 = (i1 < e) ? __int_as_float(e1.y) : 0.f;
        unsigned z0 = *(const unsigned*)(Zc + (e0.x >> 3) + d * 4);
        unsigned z1 = *(const unsigned*)(Zc + (e1.x >> 3) + d * 4);
        a0 = fmaf(w0, bf2f((unsigned short)(z0 & 0xffff)), a0);
        a1 = fmaf(w0, bf2f((unsigned short)(z0 >> 16)), a1);
        a0 = fmaf(w1, bf2f((unsigned short)(z1 & 0xffff)), a0);
        a1 = fmaf(w1, bf2f((unsigned short)(z1 >> 16)), a1);
    }
    a0 += __shfl_xor(a0, 8, 64);  a1 += __shfl_xor(a1, 8, 64);
    a0 += __shfl_xor(a0, 16, 64); a1 += __shfl_xor(a1, 16, 64);
    a0 += __shfl_xor(a0, 32, 64); a1 += __shfl_xor(a1, 32, 64);

    const int j = lane & 15;
    float e0v = __shfl(a0, j >> 1, 64);
    float e1v = __shfl(a1, j >> 1, 64);
    float accj = (j & 1) ? e1v : e0v;

    float h2 = fmaxf(accj + b2[j], 0.f);
    float s3 = 0.f;
#pragma unroll
    for (int k = 0; k < G; ++k) s3 = fmaf(__shfl(h2, k, 64), WlS[k * G + j], s3);
    float h3 = fmaxf(s3 + bl[j], 0.f);
    float m = h3;
    m = fmaxf(m, __shfl_xor(m, 1, 64));
    m = fmaxf(m, __shfl_xor(m, 2, 64));
    m = fmaxf(m, __shfl_xor(m, 4, 64));
    m = fmaxf(m, __shfl_xor(m, 8, 64));
    float ex = __expf(h3 - m);
    float se = ex;
    se += __shfl_xor(se, 1, 64);
    se += __shfl_xor(se, 2, 64);
    se += __shfl_xor(se, 4, 64);
    se += __shfl_xor(se, 8, 64);
    float y = ex / se;
    if (lane < G) {
        Yb[n * G + j] = f2bf(y);
        atomicAdd(&gsh[j], y * Dv[n]);
    }
    __syncthreads();
    if (tid < G) atomicAdd(&GammaP[(blockIdx.x & 63) * G + tid], gsh[tid]);
}

// ---------------- Gamma finalize ----------------
__global__ void k_gfin(const float* __restrict__ GammaP, float* __restrict__ invG) {
    int j = threadIdx.x;
    if (j < G) {
        float s = 0.f;
        for (int b = 0; b < 64; ++b) s += GammaP[b * G + j];
        invG[j] = 1.0f / s;
    }
}

// ---------------- edge loss (CSR, wave per node, bf16 Y) ----------------
__global__ __launch_bounds__(256) void k_loss(const unsigned short* __restrict__ Yb, const int* __restrict__ rowptr,
                                              const int2* __restrict__ E, const float* __restrict__ invG,
                                              float* __restrict__ lossAcc) {
    __shared__ float pw[4];
    const int tid = threadIdx.x;
    const int lane = tid & 63;
    const int g = lane >> 3;      // edge slot 0..7
    const int d = lane & 7;       // dword in Y row
    const int n = blockIdx.x * 4 + (tid >> 6);
    const int s = __builtin_amdgcn_readfirstlane(rowptr[n]);
    const int e = __builtin_amdgcn_readfirstlane(rowptr[n + 1]);
    const char* Yc = (const char*)Yb;

    // own Y row premultiplied by invGamma (per-lane: 2 j-entries at dword d)
    unsigned yr = *(const unsigned*)(Yc + ((size_t)n << 5) + d * 4);
    float yg0 = bf2f((unsigned short)(yr & 0xffff)) * invG[2 * d];
    float yg1 = bf2f((unsigned short)(yr >> 16))    * invG[2 * d + 1];

    float part = 0.f;
    for (int base = s; base < e; base += 16) {
        int i0 = base + g;
        int i1 = base + 8 + g;
        int2 e0 = E[(i0 < e) ? i0 : s];
        int2 e1 = E[(i1 < e) ? i1 : s];
        float w0 = (i0 < e) ? __int_as_float(e0.y) : 0.f;
        float w1 = (i1 < e) ? __int_as_float(e1.y) : 0.f;
        unsigned z0 = *(const unsigned*)(Yc + (e0.x >> 3) + d * 4);
        unsigned z1 = *(const unsigned*)(Yc + (e1.x >> 3) + d * 4);
        float t0 = yg0 * bf2f((unsigned short)(z0 & 0xffff)) + yg1 * bf2f((unsigned short)(z0 >> 16));
        float t1 = yg0 * bf2f((unsigned short)(z1 & 0xffff)) + yg1 * bf2f((unsigned short)(z1 >> 16));
        part = fmaf(w0, t0, part);
        part = fmaf(w1, t1, part);
    }
#pragma unroll
    for (int off = 1; off < 64; off <<= 1) part += __shfl_xor(part, off, 64);
    if (lane == 0) pw[tid >> 6] = part;
    __syncthreads();
    if (tid == 0) atomicAdd(lossAcc, pw[0] + pw[1] + pw[2] + pw[3]);
}

__global__ void k_final(const float* __restrict__ lossAcc, float* __restrict__ out) {
    out[0] = 16.0f - lossAcc[0];
}

// ---------------- launcher ----------------
static inline size_t alignup(size_t x) { return (x + 255) & ~(size_t)255; }

extern "C" void kernel_launch(void* const* d_in, const int* in_sizes, int n_in,
                              void* d_out, int out_size, void* d_ws, size_t ws_size,
                              hipStream_t stream) {
    const float* H  = (const float*)d_in[0];
    const int*   ei = (const int*)d_in[1];
    const float* ev = (const float*)d_in[2];
    const float* W1 = (const float*)d_in[3];
    const float* b1 = (const float*)d_in[4];
    const float* W2 = (const float*)d_in[5];
    const float* b2 = (const float*)d_in[6];
    const float* Wl = (const float*)d_in[7];
    const float* bl = (const float*)d_in[8];
    const int* row = ei;
    const int* col = ei + NE;

    char* base = (char*)d_ws;
    size_t off = 0;
    unsigned char*  XW  = (unsigned char*)(base + off);  off = alignup(off + (size_t)NN * F1);
    unsigned short* W1t = (unsigned short*)(base + off); off = alignup(off + (size_t)F0 * F1 * 2);
    unsigned short* Z   = (unsigned short*)(base + off); off = alignup(off + (size_t)NN * G * 2);
    unsigned short* Yb  = (unsigned short*)(base + off); off = alignup(off + (size_t)NN * G * 2);
    float* Dv     = (float*)(base + off); off = alignup(off + (size_t)NN * 4);
    float* GammaP = (float*)(base + off); off = alignup(off + (size_t)64 * G * 4);
    float* invG   = (float*)(base + off); off = alignup(off + (size_t)G * 4);
    float* lossA  = (float*)(base + off); off = alignup(off + 4);
    int*   counts = (int*)(base + off);   off = alignup(off + (size_t)NN * 4);
    int*   rowptr = (int*)(base + off);   off = alignup(off + (size_t)(NN + 1) * 4);
    int*   cursor = (int*)(base + off);   off = alignup(off + (size_t)NN * 4);
    int*   bsum   = (int*)(base + off);   off = alignup(off + (size_t)NB * 4);
    int*   bofs   = (int*)(base + off);   off = alignup(off + (size_t)NB * 4);
    int2*  E      = (int2*)(base + off);  off = alignup(off + (size_t)NE * 8);

    hipMemsetAsync(counts, 0, (size_t)NN * 4, stream);
    hipMemsetAsync(GammaP, 0, (size_t)64 * G * 4, stream);
    hipMemsetAsync(lossA, 0, 4, stream);

    k_hist<<<dim3((NE / 4 + 255) / 256), dim3(256), 0, stream>>>(row, counts);
    k_scan1<<<dim3(NB), dim3(1024), 0, stream>>>(counts, bsum);
    k_scan2<<<dim3(1), dim3(64), 0, stream>>>(bsum, bofs, rowptr);
    k_scan3<<<dim3(NB), dim3(1024), 0, stream>>>(counts, bofs, rowptr, cursor);
    k_scatter<<<dim3((NE / 4 + 255) / 256), dim3(256), 0, stream>>>(row, col, ev, cursor, E);
    k_castW1<<<dim3((F0 * F1 + 255) / 256), dim3(256), 0, stream>>>(W1, W1t);
    k_gemm1<<<dim3((NN + 127) / 128, F1 / 128), dim3(256), 0, stream>>>(H, W1t, XW);
    k_spmm1<<<dim3(NN / 4), dim3(256), 0, stream>>>(XW, rowptr, E, b1, W2, Z, Dv);
    k_head<<<dim3(NN / 4), dim3(256), 0, stream>>>(Z, rowptr, E, b2, Wl, bl, Dv, Yb, GammaP);
    k_gfin<<<dim3(1), dim3(64), 0, stream>>>(GammaP, invG);
    k_loss<<<dim3(NN / 4), dim3(256), 0, stream>>>(Yb, rowptr, E, invG, lossA);
    k_final<<<dim3(1), dim3(1), 0, stream>>>(lossA, (float*)d_out);
}

// Round 8
// 578.047 us; speedup vs baseline: 1.2250x; 1.2250x over previous
//
#include <hip/hip_runtime.h>

// GCN forward + NCut loss on MI355X.
// R8: R7 + k_loss partial-sum slots (256-way, blockIdx-keyed) replacing the
//     single same-address atomic that serialized 12500 blocks across XCDs.
// loss = 16 - sum_e w_e * sum_j Y[row,j]*Y[col,j]/Gamma[j]

constexpr int NN = 50000;
constexpr int NE = 1600000;
constexpr int F0 = 512;
constexpr int F1 = 256;
constexpr int G  = 16;
constexpr int NB = (NN + 1023) / 1024;   // 49 scan blocks
constexpr int LSLOTS = 256;

typedef short  s16x8 __attribute__((ext_vector_type(8)));
typedef float  f32x4 __attribute__((ext_vector_type(4)));
typedef float  f32x2 __attribute__((ext_vector_type(2)));
typedef int    i32x4 __attribute__((ext_vector_type(4)));
typedef float  fv4   __attribute__((ext_vector_type(4)));

static __device__ __forceinline__ unsigned short f2bf(float f) {
    union { float f; unsigned u; } v; v.f = f;
    unsigned r = (v.u + 0x7FFFu + ((v.u >> 16) & 1u)) >> 16;   // RNE
    return (unsigned short)r;
}
static __device__ __forceinline__ float bf2f(unsigned short u) {
    union { unsigned u; float f; } v; v.u = (unsigned)u << 16;
    return v.f;
}

// ---------------- CSR build ----------------
__global__ __launch_bounds__(256) void k_hist(const int* __restrict__ row, int* __restrict__ counts) {
    int idx = blockIdx.x * 256 + threadIdx.x;
    if (idx < NE / 4) {
        i32x4 r = __builtin_nontemporal_load(&((const i32x4*)row)[idx]);
        atomicAdd(&counts[r.x], 1);
        atomicAdd(&counts[r.y], 1);
        atomicAdd(&counts[r.z], 1);
        atomicAdd(&counts[r.w], 1);
    }
}

__global__ __launch_bounds__(1024) void k_scan1(const int* __restrict__ counts, int* __restrict__ bsum) {
    __shared__ int sh[1024];
    const int tid = threadIdx.x;
    int i = blockIdx.x * 1024 + tid;
    sh[tid] = (i < NN) ? counts[i] : 0;
    __syncthreads();
    for (int off = 512; off > 0; off >>= 1) {
        if (tid < off) sh[tid] += sh[tid + off];
        __syncthreads();
    }
    if (tid == 0) bsum[blockIdx.x] = sh[0];
}

__global__ void k_scan2(const int* __restrict__ bsum, int* __restrict__ bofs, int* __restrict__ rowptr) {
    const int tid = threadIdx.x;   // 64 threads, NB=49
    int orig = (tid < NB) ? bsum[tid] : 0;
    int v = orig;
    for (int off = 1; off < 64; off <<= 1) {
        int t = __shfl_up(v, off, 64);
        if (tid >= off) v += t;
    }
    if (tid < NB) bofs[tid] = v - orig;   // exclusive
    if (tid == 63) rowptr[NN] = v;
}

__global__ __launch_bounds__(1024) void k_scan3(const int* __restrict__ counts, const int* __restrict__ bofs,
                                                int* __restrict__ rowptr, int* __restrict__ cursor) {
    __shared__ int sh[1024];
    const int tid = threadIdx.x;
    int i = blockIdx.x * 1024 + tid;
    int orig = (i < NN) ? counts[i] : 0;
    sh[tid] = orig;
    __syncthreads();
    for (int off = 1; off < 1024; off <<= 1) {
        int t = (tid >= off) ? sh[tid - off] : 0;
        __syncthreads();
        sh[tid] += t;
        __syncthreads();
    }
    int ex = sh[tid] - orig + bofs[blockIdx.x];
    if (i < NN) { rowptr[i] = ex; cursor[i] = ex; }
}

// fused edge record: {col byte-offset into XW (c<<8), float weight bits}
__global__ __launch_bounds__(256) void k_scatter(const int* __restrict__ row, const int* __restrict__ col,
                                                 const float* __restrict__ ev, int* __restrict__ cursor,
                                                 int2* __restrict__ E) {
    int idx = blockIdx.x * 256 + threadIdx.x;
    if (idx < NE / 4) {
        i32x4 r = __builtin_nontemporal_load(&((const i32x4*)row)[idx]);
        i32x4 c = __builtin_nontemporal_load(&((const i32x4*)col)[idx]);
        fv4   w = __builtin_nontemporal_load(&((const fv4*)ev)[idx]);
        int p;
        p = atomicAdd(&cursor[r.x], 1); E[p] = make_int2(c.x << 8, __float_as_int(w.x));
        p = atomicAdd(&cursor[r.y], 1); E[p] = make_int2(c.y << 8, __float_as_int(w.y));
        p = atomicAdd(&cursor[r.z], 1); E[p] = make_int2(c.z << 8, __float_as_int(w.z));
        p = atomicAdd(&cursor[r.w], 1); E[p] = make_int2(c.w << 8, __float_as_int(w.w));
    }
}

// ---------------- W1 pre-cast+transpose ----------------
__global__ __launch_bounds__(256) void k_castW1(const float* __restrict__ W1, unsigned short* __restrict__ W1t) {
    int idx = blockIdx.x * 256 + threadIdx.x;
    if (idx < F0 * F1) {
        int k = idx >> 8, n = idx & 255;
        W1t[n * F0 + k] = f2bf(W1[idx]);
    }
}

// ---------------- GEMM1 (bf16 MFMA): XW = fp8(H @ W1) ----------------
__global__ __launch_bounds__(256) void k_gemm1(const float* __restrict__ H, const unsigned short* __restrict__ W1t,
                                               unsigned char* __restrict__ XW) {
    __shared__ unsigned short As[128][72];
    __shared__ unsigned short Bs[128][72];
    const int tid  = threadIdx.x;
    const int lane = tid & 63;
    const int wave = tid >> 6;
    const int bm = blockIdx.x * 128;
    const int bn = blockIdx.y * 128;
    const int m_off = (wave & 1) * 64;
    const int n_off = (wave >> 1) * 64;
    const int l15  = lane & 15;
    const int quad = lane >> 4;

    f32x4 acc[4][4];
#pragma unroll
    for (int i = 0; i < 4; ++i)
#pragma unroll
        for (int j = 0; j < 4; ++j) acc[i][j] = (f32x4)0.f;

    const int arow = tid >> 4;
    const int akq  = tid & 15;
    const int brow = tid >> 3;
    const int bkq  = tid & 7;

    for (int k0 = 0; k0 < F0; k0 += 64) {
        __syncthreads();
#pragma unroll
        for (int p = 0; p < 8; ++p) {
            int r = p * 16 + arow;
            int gr = bm + r;
            float4 a4 = make_float4(0.f, 0.f, 0.f, 0.f);
            if (gr < NN) a4 = *(const float4*)&H[(size_t)gr * F0 + k0 + akq * 4];
            unsigned short* dst = &As[r][akq * 4];
            dst[0] = f2bf(a4.x); dst[1] = f2bf(a4.y); dst[2] = f2bf(a4.z); dst[3] = f2bf(a4.w);
        }
#pragma unroll
        for (int p = 0; p < 4; ++p) {
            int n = p * 32 + brow;
            uint4 b8 = *(const uint4*)&W1t[(bn + n) * F0 + k0 + bkq * 8];
            *(uint4*)&Bs[n][bkq * 8] = b8;
        }
        __syncthreads();
#pragma unroll
        for (int kk = 0; kk < 64; kk += 32) {
            s16x8 af[4], bfr[4];
#pragma unroll
            for (int mi = 0; mi < 4; ++mi)
                af[mi] = *(const s16x8*)&As[m_off + mi * 16 + l15][kk + quad * 8];
#pragma unroll
            for (int ni = 0; ni < 4; ++ni)
                bfr[ni] = *(const s16x8*)&Bs[n_off + ni * 16 + l15][kk + quad * 8];
#pragma unroll
            for (int mi = 0; mi < 4; ++mi)
#pragma unroll
                for (int ni = 0; ni < 4; ++ni)
                    acc[mi][ni] = __builtin_amdgcn_mfma_f32_16x16x32_bf16(af[mi], bfr[ni], acc[mi][ni], 0, 0, 0);
        }
    }
#pragma unroll
    for (int mi = 0; mi < 4; ++mi) {
        int r0 = bm + m_off + mi * 16 + quad * 4;
#pragma unroll
        for (int reg = 0; reg < 4; ++reg) {
            int gr = r0 + reg;
            if (gr < NN) {
                unsigned char* orow = &XW[(size_t)gr * F1 + bn + n_off];
#pragma unroll
                for (int ni = 0; ni < 4; ++ni) {
                    int pk = __builtin_amdgcn_cvt_pk_fp8_f32(acc[mi][ni][reg], 0.f, 0, false);
                    orow[ni * 16 + l15] = (unsigned char)(pk & 0xff);
                }
            }
        }
    }
}

// ---------------- SPMM1 + bias + relu + fused GEMM2 (fp8 gather) ----------------
__global__ __launch_bounds__(256) void k_spmm1(const unsigned char* __restrict__ XW, const int* __restrict__ rowptr,
                                               const int2* __restrict__ E,
                                               const float* __restrict__ b1, const float* __restrict__ W2,
                                               unsigned short* __restrict__ Z, float* __restrict__ Dv) {
    __shared__ float W2T[G * F1];
    const int tid = threadIdx.x;
#pragma unroll
    for (int it = 0; it < 16; ++it)
        W2T[it * 256 + tid] = W2[tid * 16 + it];   // conflict-free writes
    __syncthreads();
    const int lane = tid & 63;
    const int lane4 = lane * 4;
    const int n = blockIdx.x * 4 + (tid >> 6);
    const int s = __builtin_amdgcn_readfirstlane(rowptr[n]);
    const int e = __builtin_amdgcn_readfirstlane(rowptr[n + 1]);

    float4 acc = make_float4(0.f, 0.f, 0.f, 0.f);
    float wsum = 0.f;
    int i = s;
    for (; i + 8 <= e; i += 8) {
        int of[8]; float w[8];
#pragma unroll
        for (int k = 0; k < 8; ++k) {
            int2 ed = E[i + k];
            of[k] = ed.x; w[k] = __int_as_float(ed.y);
        }
        unsigned gg[8];
#pragma unroll
        for (int k = 0; k < 8; ++k) gg[k] = *(const unsigned*)(XW + of[k] + lane4);
#pragma unroll
        for (int k = 0; k < 8; ++k) {
            f32x2 lo = __builtin_amdgcn_cvt_pk_f32_fp8(gg[k], false);
            f32x2 hi = __builtin_amdgcn_cvt_pk_f32_fp8(gg[k], true);
            acc.x = fmaf(w[k], lo.x, acc.x); acc.y = fmaf(w[k], lo.y, acc.y);
            acc.z = fmaf(w[k], hi.x, acc.z); acc.w = fmaf(w[k], hi.y, acc.w);
            wsum += w[k];
        }
    }
    for (; i < e; i += 4) {
        int of[4]; float w[4];
#pragma unroll
        for (int k = 0; k < 4; ++k) {
            int idx = i + k;
            bool ok = idx < e;
            int2 ed = E[ok ? idx : s];
            of[k] = ed.x; w[k] = ok ? __int_as_float(ed.y) : 0.f;
        }
        unsigned gg[4];
#pragma unroll
        for (int k = 0; k < 4; ++k) gg[k] = *(const unsigned*)(XW + of[k] + lane4);
#pragma unroll
        for (int k = 0; k < 4; ++k) {
            f32x2 lo = __builtin_amdgcn_cvt_pk_f32_fp8(gg[k], false);
            f32x2 hi = __builtin_amdgcn_cvt_pk_f32_fp8(gg[k], true);
            acc.x = fmaf(w[k], lo.x, acc.x); acc.y = fmaf(w[k], lo.y, acc.y);
            acc.z = fmaf(w[k], hi.x, acc.z); acc.w = fmaf(w[k], hi.y, acc.w);
            wsum += w[k];
        }
    }
    if (lane == 0) Dv[n] = wsum;

    float4 bb = *(const float4*)&b1[lane * 4];
    float4 h;
    h.x = fmaxf(acc.x + bb.x, 0.f);
    h.y = fmaxf(acc.y + bb.y, 0.f);
    h.z = fmaxf(acc.z + bb.z, 0.f);
    h.w = fmaxf(acc.w + bb.w, 0.f);

    float p[G];
#pragma unroll
    for (int j = 0; j < G; ++j) {
        float4 w4 = *(const float4*)&W2T[j * F1 + lane * 4];
        p[j] = h.x * w4.x + h.y * w4.y + h.z * w4.z + h.w * w4.w;
    }
#pragma unroll
    for (int off = 1; off < 64; off <<= 1) {
#pragma unroll
        for (int j = 0; j < G; ++j) p[j] += __shfl_xor(p[j], off, 64);
    }
    if (lane == 0) {
        unsigned zp[8];
#pragma unroll
        for (int j = 0; j < 8; ++j)
            zp[j] = (unsigned)f2bf(p[2 * j]) | ((unsigned)f2bf(p[2 * j + 1]) << 16);
        uint4* zo = (uint4*)&Z[n * G];
        zo[0] = make_uint4(zp[0], zp[1], zp[2], zp[3]);
        zo[1] = make_uint4(zp[4], zp[5], zp[6], zp[7]);
    }
}

// ---------------- SPMM2 + head + softmax + Gamma: 8 edges per gather instr ----------------
__global__ __launch_bounds__(256) void k_head(const unsigned short* __restrict__ Zb, const int* __restrict__ rowptr,
                                              const int2* __restrict__ E,
                                              const float* __restrict__ b2, const float* __restrict__ Wl,
                                              const float* __restrict__ bl, const float* __restrict__ Dv,
                                              unsigned short* __restrict__ Yb, float* __restrict__ GammaP) {
    __shared__ float WlS[G * G];
    __shared__ float gsh[G];
    const int tid = threadIdx.x;
    if (tid < G * G) WlS[tid] = Wl[tid];
    if (tid < G) gsh[tid] = 0.f;
    __syncthreads();
    const int lane = tid & 63;
    const int g = lane >> 3;      // edge slot 0..7
    const int d = lane & 7;       // dword in Z row
    const int n = blockIdx.x * 4 + (tid >> 6);
    const int s = __builtin_amdgcn_readfirstlane(rowptr[n]);
    const int e = __builtin_amdgcn_readfirstlane(rowptr[n + 1]);
    const char* Zc = (const char*)Zb;

    float a0 = 0.f, a1 = 0.f;
    for (int base = s; base < e; base += 16) {
        int i0 = base + g;
        int i1 = base + 8 + g;
        int2 e0 = E[(i0 < e) ? i0 : s];
        int2 e1 = E[(i1 < e) ? i1 : s];
        float w0 = (i0 < e) ? __int_as_float(e0.y) : 0.f;
        float w1 = (i1 < e) ? __int_as_float(e1.y) : 0.f;
        unsigned z0 = *(const unsigned*)(Zc + (e0.x >> 3) + d * 4);
        unsigned z1 = *(const unsigned*)(Zc + (e1.x >> 3) + d * 4);
        a0 = fmaf(w0, bf2f((unsigned short)(z0 & 0xffff)), a0);
        a1 = fmaf(w0, bf2f((unsigned short)(z0 >> 16)), a1);
        a0 = fmaf(w1, bf2f((unsigned short)(z1 & 0xffff)), a0);
        a1 = fmaf(w1, bf2f((unsigned short)(z1 >> 16)), a1);
    }
    a0 += __shfl_xor(a0, 8, 64);  a1 += __shfl_xor(a1, 8, 64);
    a0 += __shfl_xor(a0, 16, 64); a1 += __shfl_xor(a1, 16, 64);
    a0 += __shfl_xor(a0, 32, 64); a1 += __shfl_xor(a1, 32, 64);

    const int j = lane & 15;
    float e0v = __shfl(a0, j >> 1, 64);
    float e1v = __shfl(a1, j >> 1, 64);
    float accj = (j & 1) ? e1v : e0v;

    float h2 = fmaxf(accj + b2[j], 0.f);
    float s3 = 0.f;
#pragma unroll
    for (int k = 0; k < G; ++k) s3 = fmaf(__shfl(h2, k, 64), WlS[k * G + j], s3);
    float h3 = fmaxf(s3 + bl[j], 0.f);
    float m = h3;
    m = fmaxf(m, __shfl_xor(m, 1, 64));
    m = fmaxf(m, __shfl_xor(m, 2, 64));
    m = fmaxf(m, __shfl_xor(m, 4, 64));
    m = fmaxf(m, __shfl_xor(m, 8, 64));
    float ex = __expf(h3 - m);
    float se = ex;
    se += __shfl_xor(se, 1, 64);
    se += __shfl_xor(se, 2, 64);
    se += __shfl_xor(se, 4, 64);
    se += __shfl_xor(se, 8, 64);
    float y = ex / se;
    if (lane < G) {
        Yb[n * G + j] = f2bf(y);
        atomicAdd(&gsh[j], y * Dv[n]);
    }
    __syncthreads();
    if (tid < G) atomicAdd(&GammaP[(blockIdx.x & 63) * G + tid], gsh[tid]);
}

// ---------------- Gamma finalize ----------------
__global__ void k_gfin(const float* __restrict__ GammaP, float* __restrict__ invG) {
    int j = threadIdx.x;
    if (j < G) {
        float s = 0.f;
        for (int b = 0; b < 64; ++b) s += GammaP[b * G + j];
        invG[j] = 1.0f / s;
    }
}

// ---------------- edge loss (CSR, wave per node, bf16 Y, slotted partials) ----------------
__global__ __launch_bounds__(256) void k_loss(const unsigned short* __restrict__ Yb, const int* __restrict__ rowptr,
                                              const int2* __restrict__ E, const float* __restrict__ invG,
                                              float* __restrict__ lossP) {
    __shared__ float pw[4];
    const int tid = threadIdx.x;
    const int lane = tid & 63;
    const int g = lane >> 3;      // edge slot 0..7
    const int d = lane & 7;       // dword in Y row
    const int n = blockIdx.x * 4 + (tid >> 6);
    const int s = __builtin_amdgcn_readfirstlane(rowptr[n]);
    const int e = __builtin_amdgcn_readfirstlane(rowptr[n + 1]);
    const char* Yc = (const char*)Yb;

    // own Y row premultiplied by invGamma (per-lane: 2 j-entries at dword d)
    unsigned yr = *(const unsigned*)(Yc + ((size_t)n << 5) + d * 4);
    float yg0 = bf2f((unsigned short)(yr & 0xffff)) * invG[2 * d];
    float yg1 = bf2f((unsigned short)(yr >> 16))    * invG[2 * d + 1];

    float part = 0.f;
    for (int base = s; base < e; base += 16) {
        int i0 = base + g;
        int i1 = base + 8 + g;
        int2 e0 = E[(i0 < e) ? i0 : s];
        int2 e1 = E[(i1 < e) ? i1 : s];
        float w0 = (i0 < e) ? __int_as_float(e0.y) : 0.f;
        float w1 = (i1 < e) ? __int_as_float(e1.y) : 0.f;
        unsigned z0 = *(const unsigned*)(Yc + (e0.x >> 3) + d * 4);
        unsigned z1 = *(const unsigned*)(Yc + (e1.x >> 3) + d * 4);
        float t0 = yg0 * bf2f((unsigned short)(z0 & 0xffff)) + yg1 * bf2f((unsigned short)(z0 >> 16));
        float t1 = yg0 * bf2f((unsigned short)(z1 & 0xffff)) + yg1 * bf2f((unsigned short)(z1 >> 16));
        part = fmaf(w0, t0, part);
        part = fmaf(w1, t1, part);
    }
#pragma unroll
    for (int off = 1; off < 64; off <<= 1) part += __shfl_xor(part, off, 64);
    if (lane == 0) pw[tid >> 6] = part;
    __syncthreads();
    if (tid == 0) atomicAdd(&lossP[blockIdx.x & (LSLOTS - 1)], pw[0] + pw[1] + pw[2] + pw[3]);
}

__global__ void k_final(const float* __restrict__ lossP, float* __restrict__ out) {
    // 64 threads: each sums 4 slots, then wave-reduce
    const int tid = threadIdx.x;
    float s = lossP[tid] + lossP[tid + 64] + lossP[tid + 128] + lossP[tid + 192];
#pragma unroll
    for (int off = 1; off < 64; off <<= 1) s += __shfl_xor(s, off, 64);
    if (tid == 0) out[0] = 16.0f - s;
}

// ---------------- launcher ----------------
static inline size_t alignup(size_t x) { return (x + 255) & ~(size_t)255; }

extern "C" void kernel_launch(void* const* d_in, const int* in_sizes, int n_in,
                              void* d_out, int out_size, void* d_ws, size_t ws_size,
                              hipStream_t stream) {
    const float* H  = (const float*)d_in[0];
    const int*   ei = (const int*)d_in[1];
    const float* ev = (const float*)d_in[2];
    const float* W1 = (const float*)d_in[3];
    const float* b1 = (const float*)d_in[4];
    const float* W2 = (const float*)d_in[5];
    const float* b2 = (const float*)d_in[6];
    const float* Wl = (const float*)d_in[7];
    const float* bl = (const float*)d_in[8];
    const int* row = ei;
    const int* col = ei + NE;

    char* base = (char*)d_ws;
    size_t off = 0;
    unsigned char*  XW  = (unsigned char*)(base + off);  off = alignup(off + (size_t)NN * F1);
    unsigned short* W1t = (unsigned short*)(base + off); off = alignup(off + (size_t)F0 * F1 * 2);
    unsigned short* Z   = (unsigned short*)(base + off); off = alignup(off + (size_t)NN * G * 2);
    unsigned short* Yb  = (unsigned short*)(base + off); off = alignup(off + (size_t)NN * G * 2);
    float* Dv     = (float*)(base + off); off = alignup(off + (size_t)NN * 4);
    float* GammaP = (float*)(base + off); off = alignup(off + (size_t)64 * G * 4);
    float* invG   = (float*)(base + off); off = alignup(off + (size_t)G * 4);
    float* lossP  = (float*)(base + off); off = alignup(off + (size_t)LSLOTS * 4);
    int*   counts = (int*)(base + off);   off = alignup(off + (size_t)NN * 4);
    int*   rowptr = (int*)(base + off);   off = alignup(off + (size_t)(NN + 1) * 4);
    int*   cursor = (int*)(base + off);   off = alignup(off + (size_t)NN * 4);
    int*   bsum   = (int*)(base + off);   off = alignup(off + (size_t)NB * 4);
    int*   bofs   = (int*)(base + off);   off = alignup(off + (size_t)NB * 4);
    int2*  E      = (int2*)(base + off);  off = alignup(off + (size_t)NE * 8);

    hipMemsetAsync(counts, 0, (size_t)NN * 4, stream);
    hipMemsetAsync(GammaP, 0, (size_t)64 * G * 4, stream);
    hipMemsetAsync(lossP, 0, (size_t)LSLOTS * 4, stream);

    k_hist<<<dim3((NE / 4 + 255) / 256), dim3(256), 0, stream>>>(row, counts);
    k_scan1<<<dim3(NB), dim3(1024), 0, stream>>>(counts, bsum);
    k_scan2<<<dim3(1), dim3(64), 0, stream>>>(bsum, bofs, rowptr);
    k_scan3<<<dim3(NB), dim3(1024), 0, stream>>>(counts, bofs, rowptr, cursor);
    k_scatter<<<dim3((NE / 4 + 255) / 256), dim3(256), 0, stream>>>(row, col, ev, cursor, E);
    k_castW1<<<dim3((F0 * F1 + 255) / 256), dim3(256), 0, stream>>>(W1, W1t);
    k_gemm1<<<dim3((NN + 127) / 128, F1 / 128), dim3(256), 0, stream>>>(H, W1t, XW);
    k_spmm1<<<dim3(NN / 4), dim3(256), 0, stream>>>(XW, rowptr, E, b1, W2, Z, Dv);
    k_head<<<dim3(NN / 4), dim3(256), 0, stream>>>(Z, rowptr, E, b2, Wl, bl, Dv, Yb, GammaP);
    k_gfin<<<dim3(1), dim3(64), 0, stream>>>(GammaP, invG);
    k_loss<<<dim3(NN / 4), dim3(256), 0, stream>>>(Yb, rowptr, E, invG, lossP);
    k_final<<<dim3(1), dim3(64), 0, stream>>>(lossP, (float*)d_out);
}

// Round 9
// 489.597 us; speedup vs baseline: 1.4462x; 1.1807x over previous
//
#include <hip/hip_runtime.h>

// GCN forward + NCut loss on MI355X.
// R9: two-level counting scatter replaces hist+scatter:
//     passA: chunked LDS-histogram -> 196 coarse buckets (row>>8), contiguous-run
//            writes into staging; fuses per-row global histogram.
//     passB: block per coarse bucket, per-row LDS cursors, final E writes land in
//            one contiguous 64KB span per block (no write amplification).
// loss = 16 - sum_e w_e * sum_j Y[row,j]*Y[col,j]/Gamma[j]

constexpr int NN = 50000;
constexpr int NE = 1600000;
constexpr int F0 = 512;
constexpr int F1 = 256;
constexpr int G  = 16;
constexpr int NB = (NN + 1023) / 1024;   // 49 scan blocks
constexpr int LSLOTS = 256;
constexpr int CB   = 196;      // coarse buckets: row>>8 (50000/256)
constexpr int CCAP = 10240;    // capacity per coarse bucket (mean 8192, +22 sigma)
constexpr int CHUNK = 4096;    // edges per passA block

typedef short  s16x8 __attribute__((ext_vector_type(8)));
typedef float  f32x4 __attribute__((ext_vector_type(4)));
typedef float  f32x2 __attribute__((ext_vector_type(2)));
typedef int    i32x4 __attribute__((ext_vector_type(4)));
typedef float  fv4   __attribute__((ext_vector_type(4)));

static __device__ __forceinline__ unsigned short f2bf(float f) {
    union { float f; unsigned u; } v; v.f = f;
    unsigned r = (v.u + 0x7FFFu + ((v.u >> 16) & 1u)) >> 16;   // RNE
    return (unsigned short)r;
}
static __device__ __forceinline__ float bf2f(unsigned short u) {
    union { unsigned u; float f; } v; v.u = (unsigned)u << 16;
    return v.f;
}

// ---------------- passA: coarse scatter + fused row histogram ----------------
__global__ __launch_bounds__(256) void k_passA(const int* __restrict__ row, const int* __restrict__ col,
                                               const float* __restrict__ ev, int* __restrict__ counts,
                                               int* __restrict__ ccur, int2* __restrict__ cbuf) {
    __shared__ int hcnt[CB];
    __shared__ int hbase[CB];
    const int tid = threadIdx.x;
    for (int i = tid; i < CB; i += 256) hcnt[i] = 0;
    __syncthreads();

    const int base4 = blockIdx.x * (CHUNK / 4);   // int4 units
    int  recx[16]; float recw[16]; int cb[16];
#pragma unroll
    for (int k = 0; k < 4; ++k) {
        int i4 = base4 + k * 256 + tid;
        bool ok = i4 < NE / 4;
        i32x4 r = ok ? __builtin_nontemporal_load(&((const i32x4*)row)[i4]) : (i32x4)0;
        i32x4 c = ok ? __builtin_nontemporal_load(&((const i32x4*)col)[i4]) : (i32x4)0;
        fv4   w = ok ? __builtin_nontemporal_load(&((const fv4*)ev)[i4])   : (fv4)0.f;
        int rr[4] = {r.x, r.y, r.z, r.w};
        int cc[4] = {c.x, c.y, c.z, c.w};
        float ww[4] = {w.x, w.y, w.z, w.w};
#pragma unroll
        for (int j = 0; j < 4; ++j) {
            int slot = k * 4 + j;
            if (ok) {
                atomicAdd(&counts[rr[j]], 1);          // fused global row hist
                cb[slot] = rr[j] >> 8;
                atomicAdd(&hcnt[cb[slot]], 1);
            } else {
                cb[slot] = -1;
            }
            recx[slot] = (cc[j] << 16) | (rr[j] & 255);
            recw[slot] = ww[j];
        }
    }
    __syncthreads();
    for (int i = tid; i < CB; i += 256) {
        int cnt = hcnt[i];
        hbase[i] = (cnt > 0) ? atomicAdd(&ccur[i], cnt) : 0;
        hcnt[i] = 0;                                   // reuse as local cursor
    }
    __syncthreads();
#pragma unroll
    for (int slot = 0; slot < 16; ++slot) {
        if (cb[slot] >= 0) {
            int p = hbase[cb[slot]] + atomicAdd(&hcnt[cb[slot]], 1);
            cbuf[(size_t)cb[slot] * CCAP + p] = make_int2(recx[slot], __float_as_int(recw[slot]));
        }
    }
}

// ---------------- scans (rowptr from counts) ----------------
__global__ __launch_bounds__(1024) void k_scan1(const int* __restrict__ counts, int* __restrict__ bsum) {
    __shared__ int sh[1024];
    const int tid = threadIdx.x;
    int i = blockIdx.x * 1024 + tid;
    sh[tid] = (i < NN) ? counts[i] : 0;
    __syncthreads();
    for (int off = 512; off > 0; off >>= 1) {
        if (tid < off) sh[tid] += sh[tid + off];
        __syncthreads();
    }
    if (tid == 0) bsum[blockIdx.x] = sh[0];
}

__global__ void k_scan2(const int* __restrict__ bsum, int* __restrict__ bofs, int* __restrict__ rowptr) {
    const int tid = threadIdx.x;   // 64 threads, NB=49
    int orig = (tid < NB) ? bsum[tid] : 0;
    int v = orig;
    for (int off = 1; off < 64; off <<= 1) {
        int t = __shfl_up(v, off, 64);
        if (tid >= off) v += t;
    }
    if (tid < NB) bofs[tid] = v - orig;   // exclusive
    if (tid == 63) rowptr[NN] = v;
}

__global__ __launch_bounds__(1024) void k_scan3(const int* __restrict__ counts, const int* __restrict__ bofs,
                                                int* __restrict__ rowptr) {
    __shared__ int sh[1024];
    const int tid = threadIdx.x;
    int i = blockIdx.x * 1024 + tid;
    int orig = (i < NN) ? counts[i] : 0;
    sh[tid] = orig;
    __syncthreads();
    for (int off = 1; off < 1024; off <<= 1) {
        int t = (tid >= off) ? sh[tid - off] : 0;
        __syncthreads();
        sh[tid] += t;
        __syncthreads();
    }
    int ex = sh[tid] - orig + bofs[blockIdx.x];
    if (i < NN) rowptr[i] = ex;
}

// ---------------- passB: fine scatter within coarse bucket ----------------
__global__ __launch_bounds__(256) void k_passB(const int2* __restrict__ cbuf, const int* __restrict__ ccur,
                                               const int* __restrict__ rowptr, int2* __restrict__ E) {
    __shared__ int cur[256];
    const int cbk = blockIdx.x;     // 0..195
    const int tid = threadIdx.x;
    const int r = (cbk << 8) + tid;
    cur[tid] = (r < NN) ? rowptr[r] : 0;
    __syncthreads();
    const int cnt = ccur[cbk];
    const int2* src = cbuf + (size_t)cbk * CCAP;
    for (int i = tid; i < cnt; i += 256) {
        int2 rec = src[i];
        int rl = rec.x & 255;
        int c  = (int)((unsigned)rec.x >> 16);
        int p = atomicAdd(&cur[rl], 1);
        E[p] = make_int2(c << 8, rec.y);
    }
}

// ---------------- W1 pre-cast+transpose ----------------
__global__ __launch_bounds__(256) void k_castW1(const float* __restrict__ W1, unsigned short* __restrict__ W1t) {
    int idx = blockIdx.x * 256 + threadIdx.x;
    if (idx < F0 * F1) {
        int k = idx >> 8, n = idx & 255;
        W1t[n * F0 + k] = f2bf(W1[idx]);
    }
}

// ---------------- GEMM1 (bf16 MFMA): XW = fp8(H @ W1) ----------------
__global__ __launch_bounds__(256) void k_gemm1(const float* __restrict__ H, const unsigned short* __restrict__ W1t,
                                               unsigned char* __restrict__ XW) {
    __shared__ unsigned short As[128][72];
    __shared__ unsigned short Bs[128][72];
    const int tid  = threadIdx.x;
    const int lane = tid & 63;
    const int wave = tid >> 6;
    const int bm = blockIdx.x * 128;
    const int bn = blockIdx.y * 128;
    const int m_off = (wave & 1) * 64;
    const int n_off = (wave >> 1) * 64;
    const int l15  = lane & 15;
    const int quad = lane >> 4;

    f32x4 acc[4][4];
#pragma unroll
    for (int i = 0; i < 4; ++i)
#pragma unroll
        for (int j = 0; j < 4; ++j) acc[i][j] = (f32x4)0.f;

    const int arow = tid >> 4;
    const int akq  = tid & 15;
    const int brow = tid >> 3;
    const int bkq  = tid & 7;

    for (int k0 = 0; k0 < F0; k0 += 64) {
        __syncthreads();
#pragma unroll
        for (int p = 0; p < 8; ++p) {
            int r = p * 16 + arow;
            int gr = bm + r;
            float4 a4 = make_float4(0.f, 0.f, 0.f, 0.f);
            if (gr < NN) a4 = *(const float4*)&H[(size_t)gr * F0 + k0 + akq * 4];
            unsigned short* dst = &As[r][akq * 4];
            dst[0] = f2bf(a4.x); dst[1] = f2bf(a4.y); dst[2] = f2bf(a4.z); dst[3] = f2bf(a4.w);
        }
#pragma unroll
        for (int p = 0; p < 4; ++p) {
            int n = p * 32 + brow;
            uint4 b8 = *(const uint4*)&W1t[(bn + n) * F0 + k0 + bkq * 8];
            *(uint4*)&Bs[n][bkq * 8] = b8;
        }
        __syncthreads();
#pragma unroll
        for (int kk = 0; kk < 64; kk += 32) {
            s16x8 af[4], bfr[4];
#pragma unroll
            for (int mi = 0; mi < 4; ++mi)
                af[mi] = *(const s16x8*)&As[m_off + mi * 16 + l15][kk + quad * 8];
#pragma unroll
            for (int ni = 0; ni < 4; ++ni)
                bfr[ni] = *(const s16x8*)&Bs[n_off + ni * 16 + l15][kk + quad * 8];
#pragma unroll
            for (int mi = 0; mi < 4; ++mi)
#pragma unroll
                for (int ni = 0; ni < 4; ++ni)
                    acc[mi][ni] = __builtin_amdgcn_mfma_f32_16x16x32_bf16(af[mi], bfr[ni], acc[mi][ni], 0, 0, 0);
        }
    }
#pragma unroll
    for (int mi = 0; mi < 4; ++mi) {
        int r0 = bm + m_off + mi * 16 + quad * 4;
#pragma unroll
        for (int reg = 0; reg < 4; ++reg) {
            int gr = r0 + reg;
            if (gr < NN) {
                unsigned char* orow = &XW[(size_t)gr * F1 + bn + n_off];
#pragma unroll
                for (int ni = 0; ni < 4; ++ni) {
                    int pk = __builtin_amdgcn_cvt_pk_fp8_f32(acc[mi][ni][reg], 0.f, 0, false);
                    orow[ni * 16 + l15] = (unsigned char)(pk & 0xff);
                }
            }
        }
    }
}

// ---------------- SPMM1 + bias + relu + fused GEMM2 (fp8 gather) ----------------
__global__ __launch_bounds__(256) void k_spmm1(const unsigned char* __restrict__ XW, const int* __restrict__ rowptr,
                                               const int2* __restrict__ E,
                                               const float* __restrict__ b1, const float* __restrict__ W2,
                                               unsigned short* __restrict__ Z, float* __restrict__ Dv) {
    __shared__ float W2T[G * F1];
    const int tid = threadIdx.x;
#pragma unroll
    for (int it = 0; it < 16; ++it)
        W2T[it * 256 + tid] = W2[tid * 16 + it];   // conflict-free writes
    __syncthreads();
    const int lane = tid & 63;
    const int lane4 = lane * 4;
    const int n = blockIdx.x * 4 + (tid >> 6);
    const int s = __builtin_amdgcn_readfirstlane(rowptr[n]);
    const int e = __builtin_amdgcn_readfirstlane(rowptr[n + 1]);

    float4 acc = make_float4(0.f, 0.f, 0.f, 0.f);
    float wsum = 0.f;
    int i = s;
    for (; i + 8 <= e; i += 8) {
        int of[8]; float w[8];
#pragma unroll
        for (int k = 0; k < 8; ++k) {
            int2 ed = E[i + k];
            of[k] = ed.x; w[k] = __int_as_float(ed.y);
        }
        unsigned gg[8];
#pragma unroll
        for (int k = 0; k < 8; ++k) gg[k] = *(const unsigned*)(XW + of[k] + lane4);
#pragma unroll
        for (int k = 0; k < 8; ++k) {
            f32x2 lo = __builtin_amdgcn_cvt_pk_f32_fp8(gg[k], false);
            f32x2 hi = __builtin_amdgcn_cvt_pk_f32_fp8(gg[k], true);
            acc.x = fmaf(w[k], lo.x, acc.x); acc.y = fmaf(w[k], lo.y, acc.y);
            acc.z = fmaf(w[k], hi.x, acc.z); acc.w = fmaf(w[k], hi.y, acc.w);
            wsum += w[k];
        }
    }
    for (; i < e; i += 4) {
        int of[4]; float w[4];
#pragma unroll
        for (int k = 0; k < 4; ++k) {
            int idx = i + k;
            bool ok = idx < e;
            int2 ed = E[ok ? idx : s];
            of[k] = ed.x; w[k] = ok ? __int_as_float(ed.y) : 0.f;
        }
        unsigned gg[4];
#pragma unroll
        for (int k = 0; k < 4; ++k) gg[k] = *(const unsigned*)(XW + of[k] + lane4);
#pragma unroll
        for (int k = 0; k < 4; ++k) {
            f32x2 lo = __builtin_amdgcn_cvt_pk_f32_fp8(gg[k], false);
            f32x2 hi = __builtin_amdgcn_cvt_pk_f32_fp8(gg[k], true);
            acc.x = fmaf(w[k], lo.x, acc.x); acc.y = fmaf(w[k], lo.y, acc.y);
            acc.z = fmaf(w[k], hi.x, acc.z); acc.w = fmaf(w[k], hi.y, acc.w);
            wsum += w[k];
        }
    }
    if (lane == 0) Dv[n] = wsum;

    float4 bb = *(const float4*)&b1[lane * 4];
    float4 h;
    h.x = fmaxf(acc.x + bb.x, 0.f);
    h.y = fmaxf(acc.y + bb.y, 0.f);
    h.z = fmaxf(acc.z + bb.z, 0.f);
    h.w = fmaxf(acc.w + bb.w, 0.f);

    float p[G];
#pragma unroll
    for (int j = 0; j < G; ++j) {
        float4 w4 = *(const float4*)&W2T[j * F1 + lane * 4];
        p[j] = h.x * w4.x + h.y * w4.y + h.z * w4.z + h.w * w4.w;
    }
#pragma unroll
    for (int off = 1; off < 64; off <<= 1) {
#pragma unroll
        for (int j = 0; j < G; ++j) p[j] += __shfl_xor(p[j], off, 64);
    }
    if (lane == 0) {
        unsigned zp[8];
#pragma unroll
        for (int j = 0; j < 8; ++j)
            zp[j] = (unsigned)f2bf(p[2 * j]) | ((unsigned)f2bf(p[2 * j + 1]) << 16);
        uint4* zo = (uint4*)&Z[n * G];
        zo[0] = make_uint4(zp[0], zp[1], zp[2], zp[3]);
        zo[1] = make_uint4(zp[4], zp[5], zp[6], zp[7]);
    }
}

// ---------------- SPMM2 + head + softmax + Gamma ----------------
__global__ __launch_bounds__(256) void k_head(const unsigned short* __restrict__ Zb, const int* __restrict__ rowptr,
                                              const int2* __restrict__ E,
                                              const float* __restrict__ b2, const float* __restrict__ Wl,
                                              const float* __restrict__ bl, const float* __restrict__ Dv,
                                              unsigned short* __restrict__ Yb, float* __restrict__ GammaP) {
    __shared__ float WlS[G * G];
    __shared__ float gsh[G];
    const int tid = threadIdx.x;
    if (tid < G * G) WlS[tid] = Wl[tid];
    if (tid < G) gsh[tid] = 0.f;
    __syncthreads();
    const int lane = tid & 63;
    const int g = lane >> 3;      // edge slot 0..7
    const int d = lane & 7;       // dword in Z row
    const int n = blockIdx.x * 4 + (tid >> 6);
    const int s = __builtin_amdgcn_readfirstlane(rowptr[n]);
    const int e = __builtin_amdgcn_readfirstlane(rowptr[n + 1]);
    const char* Zc = (const char*)Zb;

    float a0 = 0.f, a1 = 0.f;
    for (int base = s; base < e; base += 16) {
        int i0 = base + g;
        int i1 = base + 8 + g;
        int2 e0 = E[(i0 < e) ? i0 : s];
        int2 e1 = E[(i1 < e) ? i1 : s];
        float w0 = (i0 < e) ? __int_as_float(e0.y) : 0.f;
        float w1 = (i1 < e) ? __int_as_float(e1.y) : 0.f;
        unsigned z0 = *(const unsigned*)(Zc + (e0.x >> 3) + d * 4);
        unsigned z1 = *(const unsigned*)(Zc + (e1.x >> 3) + d * 4);
        a0 = fmaf(w0, bf2f((unsigned short)(z0 & 0xffff)), a0);
        a1 = fmaf(w0, bf2f((unsigned short)(z0 >> 16)), a1);
        a0 = fmaf(w1, bf2f((unsigned short)(z1 & 0xffff)), a0);
        a1 = fmaf(w1, bf2f((unsigned short)(z1 >> 16)), a1);
    }
    a0 += __shfl_xor(a0, 8, 64);  a1 += __shfl_xor(a1, 8, 64);
    a0 += __shfl_xor(a0, 16, 64); a1 += __shfl_xor(a1, 16, 64);
    a0 += __shfl_xor(a0, 32, 64); a1 += __shfl_xor(a1, 32, 64);

    const int j = lane & 15;
    float e0v = __shfl(a0, j >> 1, 64);
    float e1v = __shfl(a1, j >> 1, 64);
    float accj = (j & 1) ? e1v : e0v;

    float h2 = fmaxf(accj + b2[j], 0.f);
    float s3 = 0.f;
#pragma unroll
    for (int k = 0; k < G; ++k) s3 = fmaf(__shfl(h2, k, 64), WlS[k * G + j], s3);
    float h3 = fmaxf(s3 + bl[j], 0.f);
    float m = h3;
    m = fmaxf(m, __shfl_xor(m, 1, 64));
    m = fmaxf(m, __shfl_xor(m, 2, 64));
    m = fmaxf(m, __shfl_xor(m, 4, 64));
    m = fmaxf(m, __shfl_xor(m, 8, 64));
    float ex = __expf(h3 - m);
    float se = ex;
    se += __shfl_xor(se, 1, 64);
    se += __shfl_xor(se, 2, 64);
    se += __shfl_xor(se, 4, 64);
    se += __shfl_xor(se, 8, 64);
    float y = ex / se;
    if (lane < G) {
        Yb[n * G + j] = f2bf(y);
        atomicAdd(&gsh[j], y * Dv[n]);
    }
    __syncthreads();
    if (tid < G) atomicAdd(&GammaP[(blockIdx.x & 63) * G + tid], gsh[tid]);
}

// ---------------- Gamma finalize ----------------
__global__ void k_gfin(const float* __restrict__ GammaP, float* __restrict__ invG) {
    int j = threadIdx.x;
    if (j < G) {
        float s = 0.f;
        for (int b = 0; b < 64; ++b) s += GammaP[b * G + j];
        invG[j] = 1.0f / s;
    }
}

// ---------------- edge loss (CSR, wave per node, bf16 Y, slotted partials) ----------------
__global__ __launch_bounds__(256) void k_loss(const unsigned short* __restrict__ Yb, const int* __restrict__ rowptr,
                                              const int2* __restrict__ E, const float* __restrict__ invG,
                                              float* __restrict__ lossP) {
    __shared__ float pw[4];
    const int tid = threadIdx.x;
    const int lane = tid & 63;
    const int g = lane >> 3;
    const int d = lane & 7;
    const int n = blockIdx.x * 4 + (tid >> 6);
    const int s = __builtin_amdgcn_readfirstlane(rowptr[n]);
    const int e = __builtin_amdgcn_readfirstlane(rowptr[n + 1]);
    const char* Yc = (const char*)Yb;

    unsigned yr = *(const unsigned*)(Yc + ((size_t)n << 5) + d * 4);
    float yg0 = bf2f((unsigned short)(yr & 0xffff)) * invG[2 * d];
    float yg1 = bf2f((unsigned short)(yr >> 16))    * invG[2 * d + 1];

    float part = 0.f;
    for (int base = s; base < e; base += 16) {
        int i0 = base + g;
        int i1 = base + 8 + g;
        int2 e0 = E[(i0 < e) ? i0 : s];
        int2 e1 = E[(i1 < e) ? i1 : s];
        float w0 = (i0 < e) ? __int_as_float(e0.y) : 0.f;
        float w1 = (i1 < e) ? __int_as_float(e1.y) : 0.f;
        unsigned z0 = *(const unsigned*)(Yc + (e0.x >> 3) + d * 4);
        unsigned z1 = *(const unsigned*)(Yc + (e1.x >> 3) + d * 4);
        float t0 = yg0 * bf2f((unsigned short)(z0 & 0xffff)) + yg1 * bf2f((unsigned short)(z0 >> 16));
        float t1 = yg0 * bf2f((unsigned short)(z1 & 0xffff)) + yg1 * bf2f((unsigned short)(z1 >> 16));
        part = fmaf(w0, t0, part);
        part = fmaf(w1, t1, part);
    }
#pragma unroll
    for (int off = 1; off < 64; off <<= 1) part += __shfl_xor(part, off, 64);
    if (lane == 0) pw[tid >> 6] = part;
    __syncthreads();
    if (tid == 0) atomicAdd(&lossP[blockIdx.x & (LSLOTS - 1)], pw[0] + pw[1] + pw[2] + pw[3]);
}

__global__ void k_final(const float* __restrict__ lossP, float* __restrict__ out) {
    const int tid = threadIdx.x;
    float s = lossP[tid] + lossP[tid + 64] + lossP[tid + 128] + lossP[tid + 192];
#pragma unroll
    for (int off = 1; off < 64; off <<= 1) s += __shfl_xor(s, off, 64);
    if (tid == 0) out[0] = 16.0f - s;
}

// ---------------- launcher ----------------
static inline size_t alignup(size_t x) { return (x + 255) & ~(size_t)255; }

extern "C" void kernel_launch(void* const* d_in, const int* in_sizes, int n_in,
                              void* d_out, int out_size, void* d_ws, size_t ws_size,
                              hipStream_t stream) {
    const float* H  = (const float*)d_in[0];
    const int*   ei = (const int*)d_in[1];
    const float* ev = (const float*)d_in[2];
    const float* W1 = (const float*)d_in[3];
    const float* b1 = (const float*)d_in[4];
    const float* W2 = (const float*)d_in[5];
    const float* b2 = (const float*)d_in[6];
    const float* Wl = (const float*)d_in[7];
    const float* bl = (const float*)d_in[8];
    const int* row = ei;
    const int* col = ei + NE;

    char* base = (char*)d_ws;
    size_t off = 0;
    unsigned char*  XW  = (unsigned char*)(base + off);  off = alignup(off + (size_t)NN * F1);
    unsigned short* W1t = (unsigned short*)(base + off); off = alignup(off + (size_t)F0 * F1 * 2);
    unsigned short* Z   = (unsigned short*)(base + off); off = alignup(off + (size_t)NN * G * 2);
    unsigned short* Yb  = (unsigned short*)(base + off); off = alignup(off + (size_t)NN * G * 2);
    float* Dv     = (float*)(base + off); off = alignup(off + (size_t)NN * 4);
    float* GammaP = (float*)(base + off); off = alignup(off + (size_t)64 * G * 4);
    float* invG   = (float*)(base + off); off = alignup(off + (size_t)G * 4);
    float* lossP  = (float*)(base + off); off = alignup(off + (size_t)LSLOTS * 4);
    int*   counts = (int*)(base + off);   off = alignup(off + (size_t)NN * 4);
    int*   rowptr = (int*)(base + off);   off = alignup(off + (size_t)(NN + 1) * 4);
    int*   bsum   = (int*)(base + off);   off = alignup(off + (size_t)NB * 4);
    int*   bofs   = (int*)(base + off);   off = alignup(off + (size_t)NB * 4);
    int*   ccur   = (int*)(base + off);   off = alignup(off + (size_t)CB * 4);
    int2*  cbuf   = (int2*)(base + off);  off = alignup(off + (size_t)CB * CCAP * 8);
    int2*  E      = (int2*)(base + off);  off = alignup(off + (size_t)NE * 8);

    hipMemsetAsync(counts, 0, (size_t)NN * 4, stream);
    hipMemsetAsync(ccur, 0, (size_t)CB * 4, stream);
    hipMemsetAsync(GammaP, 0, (size_t)64 * G * 4, stream);
    hipMemsetAsync(lossP, 0, (size_t)LSLOTS * 4, stream);

    k_passA<<<dim3((NE + CHUNK - 1) / CHUNK), dim3(256), 0, stream>>>(row, col, ev, counts, ccur, cbuf);
    k_scan1<<<dim3(NB), dim3(1024), 0, stream>>>(counts, bsum);
    k_scan2<<<dim3(1), dim3(64), 0, stream>>>(bsum, bofs, rowptr);
    k_scan3<<<dim3(NB), dim3(1024), 0, stream>>>(counts, bofs, rowptr);
    k_passB<<<dim3(CB), dim3(256), 0, stream>>>(cbuf, ccur, rowptr, E);
    k_castW1<<<dim3((F0 * F1 + 255) / 256), dim3(256), 0, stream>>>(W1, W1t);
    k_gemm1<<<dim3((NN + 127) / 128, F1 / 128), dim3(256), 0, stream>>>(H, W1t, XW);
    k_spmm1<<<dim3(NN / 4), dim3(256), 0, stream>>>(XW, rowptr, E, b1, W2, Z, Dv);
    k_head<<<dim3(NN / 4), dim3(256), 0, stream>>>(Z, rowptr, E, b2, Wl, bl, Dv, Yb, GammaP);
    k_gfin<<<dim3(1), dim3(64), 0, stream>>>(GammaP, invG);
    k_loss<<<dim3(NN / 4), dim3(256), 0, stream>>>(Yb, rowptr, E, invG, lossP);
    k_final<<<dim3(1), dim3(64), 0, stream>>>(lossP, (float*)d_out);
}

// Round 10
// 435.624 us; speedup vs baseline: 1.6254x; 1.1239x over previous
//
#include <hip/hip_runtime.h>

// GCN forward + NCut loss on MI355X.
// R10: CSR build consolidated — passA drops the global row-histogram; passB builds
//      rowptr locally (per-bucket LDS count+scan, base from ccur prefix) and scatters.
//      16 -> 12 dispatches. Nontemporal E-stream loads in spmm1/head/loss.
// loss = 16 - sum_e w_e * sum_j Y[row,j]*Y[col,j]/Gamma[j]

constexpr int NN = 50000;
constexpr int NE = 1600000;
constexpr int F0 = 512;
constexpr int F1 = 256;
constexpr int G  = 16;
constexpr int LSLOTS = 256;
constexpr int CB   = 196;      // coarse buckets: row>>8
constexpr int CCAP = 10240;    // capacity per coarse bucket (mean 8163, +23 sigma)
constexpr int CHUNK = 4096;    // edges per passA block

typedef short  s16x8 __attribute__((ext_vector_type(8)));
typedef float  f32x4 __attribute__((ext_vector_type(4)));
typedef float  f32x2 __attribute__((ext_vector_type(2)));
typedef int    i32x4 __attribute__((ext_vector_type(4)));
typedef int    i32x2 __attribute__((ext_vector_type(2)));
typedef float  fv4   __attribute__((ext_vector_type(4)));

static __device__ __forceinline__ unsigned short f2bf(float f) {
    union { float f; unsigned u; } v; v.f = f;
    unsigned r = (v.u + 0x7FFFu + ((v.u >> 16) & 1u)) >> 16;   // RNE
    return (unsigned short)r;
}
static __device__ __forceinline__ float bf2f(unsigned short u) {
    union { unsigned u; float f; } v; v.u = (unsigned)u << 16;
    return v.f;
}

// ---------------- passA: coarse scatter into 196 buckets ----------------
__global__ __launch_bounds__(256) void k_passA(const int* __restrict__ row, const int* __restrict__ col,
                                               const float* __restrict__ ev,
                                               int* __restrict__ ccur, int2* __restrict__ cbuf) {
    __shared__ int hcnt[CB];
    __shared__ int hbase[CB];
    const int tid = threadIdx.x;
    for (int i = tid; i < CB; i += 256) hcnt[i] = 0;
    __syncthreads();

    const int base4 = blockIdx.x * (CHUNK / 4);   // int4 units
    int recx[16]; float recw[16]; int cb[16];
#pragma unroll
    for (int k = 0; k < 4; ++k) {
        int i4 = base4 + k * 256 + tid;
        bool ok = i4 < NE / 4;
        i32x4 r = ok ? __builtin_nontemporal_load(&((const i32x4*)row)[i4]) : (i32x4)0;
        i32x4 c = ok ? __builtin_nontemporal_load(&((const i32x4*)col)[i4]) : (i32x4)0;
        fv4   w = ok ? __builtin_nontemporal_load(&((const fv4*)ev)[i4])   : (fv4)0.f;
        int rr[4] = {r.x, r.y, r.z, r.w};
        int cc[4] = {c.x, c.y, c.z, c.w};
        float ww[4] = {w.x, w.y, w.z, w.w};
#pragma unroll
        for (int j = 0; j < 4; ++j) {
            int slot = k * 4 + j;
            if (ok) {
                cb[slot] = rr[j] >> 8;
                atomicAdd(&hcnt[cb[slot]], 1);
            } else {
                cb[slot] = -1;
            }
            recx[slot] = (cc[j] << 16) | (rr[j] & 255);
            recw[slot] = ww[j];
        }
    }
    __syncthreads();
    for (int i = tid; i < CB; i += 256) {
        int cnt = hcnt[i];
        hbase[i] = (cnt > 0) ? atomicAdd(&ccur[i], cnt) : 0;
        hcnt[i] = 0;                                   // reuse as local cursor
    }
    __syncthreads();
#pragma unroll
    for (int slot = 0; slot < 16; ++slot) {
        if (cb[slot] >= 0) {
            int p = hbase[cb[slot]] + atomicAdd(&hcnt[cb[slot]], 1);
            cbuf[(size_t)cb[slot] * CCAP + p] = make_int2(recx[slot], __float_as_int(recw[slot]));
        }
    }
}

// ---------------- passB: build rowptr slice + fine scatter ----------------
__global__ __launch_bounds__(256) void k_passB(const int2* __restrict__ cbuf, const int* __restrict__ ccur,
                                               int* __restrict__ rowptr, int2* __restrict__ E) {
    __shared__ int cnt[256];
    __shared__ int scn[256];
    __shared__ int red[4];
    const int cbk = blockIdx.x;     // 0..195
    const int tid = threadIdx.x;
    cnt[tid] = 0;

    // base = sum(ccur[0..cbk))
    int b = 0;
    for (int i = tid; i < cbk; i += 256) b += ccur[i];
#pragma unroll
    for (int off = 1; off < 64; off <<= 1) b += __shfl_xor(b, off, 64);
    if ((tid & 63) == 0) red[tid >> 6] = b;
    __syncthreads();
    const int base = red[0] + red[1] + red[2] + red[3];

    const int total = ccur[cbk];
    const int2* src = cbuf + (size_t)cbk * CCAP;
    for (int i = tid; i < total; i += 256) atomicAdd(&cnt[src[i].x & 255], 1);
    __syncthreads();

    // exclusive scan over 256 row counters
    scn[tid] = cnt[tid];
    __syncthreads();
    for (int off = 1; off < 256; off <<= 1) {
        int t = (tid >= off) ? scn[tid - off] : 0;
        __syncthreads();
        scn[tid] += t;
        __syncthreads();
    }
    const int excl = scn[tid] - cnt[tid];
    const int r = (cbk << 8) + tid;
    if (r <= NN) rowptr[r] = base + excl;   // block 195, tid 80 writes rowptr[NN]=NE
    __syncthreads();
    cnt[tid] = base + excl;                 // reuse as cursor
    __syncthreads();
    for (int i = tid; i < total; i += 256) {
        int2 rec = src[i];
        int rl = rec.x & 255;
        int c  = (int)((unsigned)rec.x >> 16);
        int p = atomicAdd(&cnt[rl], 1);
        E[p] = make_int2(c << 8, rec.y);
    }
}

// ---------------- W1 pre-cast+transpose ----------------
__global__ __launch_bounds__(256) void k_castW1(const float* __restrict__ W1, unsigned short* __restrict__ W1t) {
    int idx = blockIdx.x * 256 + threadIdx.x;
    if (idx < F0 * F1) {
        int k = idx >> 8, n = idx & 255;
        W1t[n * F0 + k] = f2bf(W1[idx]);
    }
}

// ---------------- GEMM1 (bf16 MFMA): XW = fp8(H @ W1) ----------------
__global__ __launch_bounds__(256) void k_gemm1(const float* __restrict__ H, const unsigned short* __restrict__ W1t,
                                               unsigned char* __restrict__ XW) {
    __shared__ unsigned short As[128][72];
    __shared__ unsigned short Bs[128][72];
    const int tid  = threadIdx.x;
    const int lane = tid & 63;
    const int wave = tid >> 6;
    const int bm = blockIdx.x * 128;
    const int bn = blockIdx.y * 128;
    const int m_off = (wave & 1) * 64;
    const int n_off = (wave >> 1) * 64;
    const int l15  = lane & 15;
    const int quad = lane >> 4;

    f32x4 acc[4][4];
#pragma unroll
    for (int i = 0; i < 4; ++i)
#pragma unroll
        for (int j = 0; j < 4; ++j) acc[i][j] = (f32x4)0.f;

    const int arow = tid >> 4;
    const int akq  = tid & 15;
    const int brow = tid >> 3;
    const int bkq  = tid & 7;

    for (int k0 = 0; k0 < F0; k0 += 64) {
        __syncthreads();
#pragma unroll
        for (int p = 0; p < 8; ++p) {
            int r = p * 16 + arow;
            int gr = bm + r;
            float4 a4 = make_float4(0.f, 0.f, 0.f, 0.f);
            if (gr < NN) a4 = *(const float4*)&H[(size_t)gr * F0 + k0 + akq * 4];
            unsigned short* dst = &As[r][akq * 4];
            dst[0] = f2bf(a4.x); dst[1] = f2bf(a4.y); dst[2] = f2bf(a4.z); dst[3] = f2bf(a4.w);
        }
#pragma unroll
        for (int p = 0; p < 4; ++p) {
            int n = p * 32 + brow;
            uint4 b8 = *(const uint4*)&W1t[(bn + n) * F0 + k0 + bkq * 8];
            *(uint4*)&Bs[n][bkq * 8] = b8;
        }
        __syncthreads();
#pragma unroll
        for (int kk = 0; kk < 64; kk += 32) {
            s16x8 af[4], bfr[4];
#pragma unroll
            for (int mi = 0; mi < 4; ++mi)
                af[mi] = *(const s16x8*)&As[m_off + mi * 16 + l15][kk + quad * 8];
#pragma unroll
            for (int ni = 0; ni < 4; ++ni)
                bfr[ni] = *(const s16x8*)&Bs[n_off + ni * 16 + l15][kk + quad * 8];
#pragma unroll
            for (int mi = 0; mi < 4; ++mi)
#pragma unroll
                for (int ni = 0; ni < 4; ++ni)
                    acc[mi][ni] = __builtin_amdgcn_mfma_f32_16x16x32_bf16(af[mi], bfr[ni], acc[mi][ni], 0, 0, 0);
        }
    }
#pragma unroll
    for (int mi = 0; mi < 4; ++mi) {
        int r0 = bm + m_off + mi * 16 + quad * 4;
#pragma unroll
        for (int reg = 0; reg < 4; ++reg) {
            int gr = r0 + reg;
            if (gr < NN) {
                unsigned char* orow = &XW[(size_t)gr * F1 + bn + n_off];
#pragma unroll
                for (int ni = 0; ni < 4; ++ni) {
                    int pk = __builtin_amdgcn_cvt_pk_fp8_f32(acc[mi][ni][reg], 0.f, 0, false);
                    orow[ni * 16 + l15] = (unsigned char)(pk & 0xff);
                }
            }
        }
    }
}

// ---------------- SPMM1 + bias + relu + fused GEMM2 (fp8 gather) ----------------
__global__ __launch_bounds__(256) void k_spmm1(const unsigned char* __restrict__ XW, const int* __restrict__ rowptr,
                                               const int2* __restrict__ E,
                                               const float* __restrict__ b1, const float* __restrict__ W2,
                                               unsigned short* __restrict__ Z, float* __restrict__ Dv) {
    __shared__ float W2T[G * F1];
    const int tid = threadIdx.x;
#pragma unroll
    for (int it = 0; it < 16; ++it)
        W2T[it * 256 + tid] = W2[tid * 16 + it];   // conflict-free writes
    __syncthreads();
    const int lane = tid & 63;
    const int lane4 = lane * 4;
    const int n = blockIdx.x * 4 + (tid >> 6);
    const int s = __builtin_amdgcn_readfirstlane(rowptr[n]);
    const int e = __builtin_amdgcn_readfirstlane(rowptr[n + 1]);
    const i32x2* Ev = (const i32x2*)E;

    float4 acc = make_float4(0.f, 0.f, 0.f, 0.f);
    float wsum = 0.f;
    int i = s;
    for (; i + 8 <= e; i += 8) {
        int of[8]; float w[8];
#pragma unroll
        for (int k = 0; k < 8; ++k) {
            i32x2 ed = __builtin_nontemporal_load(&Ev[i + k]);
            of[k] = ed.x; w[k] = __int_as_float(ed.y);
        }
        unsigned gg[8];
#pragma unroll
        for (int k = 0; k < 8; ++k) gg[k] = *(const unsigned*)(XW + of[k] + lane4);
#pragma unroll
        for (int k = 0; k < 8; ++k) {
            f32x2 lo = __builtin_amdgcn_cvt_pk_f32_fp8(gg[k], false);
            f32x2 hi = __builtin_amdgcn_cvt_pk_f32_fp8(gg[k], true);
            acc.x = fmaf(w[k], lo.x, acc.x); acc.y = fmaf(w[k], lo.y, acc.y);
            acc.z = fmaf(w[k], hi.x, acc.z); acc.w = fmaf(w[k], hi.y, acc.w);
            wsum += w[k];
        }
    }
    for (; i < e; i += 4) {
        int of[4]; float w[4];
#pragma unroll
        for (int k = 0; k < 4; ++k) {
            int idx = i + k;
            bool ok = idx < e;
            i32x2 ed = Ev[ok ? idx : s];
            of[k] = ed.x; w[k] = ok ? __int_as_float(ed.y) : 0.f;
        }
        unsigned gg[4];
#pragma unroll
        for (int k = 0; k < 4; ++k) gg[k] = *(const unsigned*)(XW + of[k] + lane4);
#pragma unroll
        for (int k = 0; k < 4; ++k) {
            f32x2 lo = __builtin_amdgcn_cvt_pk_f32_fp8(gg[k], false);
            f32x2 hi = __builtin_amdgcn_cvt_pk_f32_fp8(gg[k], true);
            acc.x = fmaf(w[k], lo.x, acc.x); acc.y = fmaf(w[k], lo.y, acc.y);
            acc.z = fmaf(w[k], hi.x, acc.z); acc.w = fmaf(w[k], hi.y, acc.w);
            wsum += w[k];
        }
    }
    if (lane == 0) Dv[n] = wsum;

    float4 bb = *(const float4*)&b1[lane * 4];
    float4 h;
    h.x = fmaxf(acc.x + bb.x, 0.f);
    h.y = fmaxf(acc.y + bb.y, 0.f);
    h.z = fmaxf(acc.z + bb.z, 0.f);
    h.w = fmaxf(acc.w + bb.w, 0.f);

    float p[G];
#pragma unroll
    for (int j = 0; j < G; ++j) {
        float4 w4 = *(const float4*)&W2T[j * F1 + lane * 4];
        p[j] = h.x * w4.x + h.y * w4.y + h.z * w4.z + h.w * w4.w;
    }
#pragma unroll
    for (int off = 1; off < 64; off <<= 1) {
#pragma unroll
        for (int j = 0; j < G; ++j) p[j] += __shfl_xor(p[j], off, 64);
    }
    if (lane == 0) {
        unsigned zp[8];
#pragma unroll
        for (int j = 0; j < 8; ++j)
            zp[j] = (unsigned)f2bf(p[2 * j]) | ((unsigned)f2bf(p[2 * j + 1]) << 16);
        uint4* zo = (uint4*)&Z[n * G];
        zo[0] = make_uint4(zp[0], zp[1], zp[2], zp[3]);
        zo[1] = make_uint4(zp[4], zp[5], zp[6], zp[7]);
    }
}

// ---------------- SPMM2 + head + softmax + Gamma ----------------
__global__ __launch_bounds__(256) void k_head(const unsigned short* __restrict__ Zb, const int* __restrict__ rowptr,
                                              const int2* __restrict__ E,
                                              const float* __restrict__ b2, const float* __restrict__ Wl,
                                              const float* __restrict__ bl, const float* __restrict__ Dv,
                                              unsigned short* __restrict__ Yb, float* __restrict__ GammaP) {
    __shared__ float WlS[G * G];
    __shared__ float gsh[G];
    const int tid = threadIdx.x;
    if (tid < G * G) WlS[tid] = Wl[tid];
    if (tid < G) gsh[tid] = 0.f;
    __syncthreads();
    const int lane = tid & 63;
    const int g = lane >> 3;      // edge slot 0..7
    const int d = lane & 7;       // dword in Z row
    const int n = blockIdx.x * 4 + (tid >> 6);
    const int s = __builtin_amdgcn_readfirstlane(rowptr[n]);
    const int e = __builtin_amdgcn_readfirstlane(rowptr[n + 1]);
    const char* Zc = (const char*)Zb;
    const i32x2* Ev = (const i32x2*)E;

    float a0 = 0.f, a1 = 0.f;
    for (int base = s; base < e; base += 16) {
        int i0 = base + g;
        int i1 = base + 8 + g;
        i32x2 e0 = __builtin_nontemporal_load(&Ev[(i0 < e) ? i0 : s]);
        i32x2 e1 = __builtin_nontemporal_load(&Ev[(i1 < e) ? i1 : s]);
        float w0 = (i0 < e) ? __int_as_float(e0.y) : 0.f;
        float w1 = (i1 < e) ? __int_as_float(e1.y) : 0.f;
        unsigned z0 = *(const unsigned*)(Zc + (e0.x >> 3) + d * 4);
        unsigned z1 = *(const unsigned*)(Zc + (e1.x >> 3) + d * 4);
        a0 = fmaf(w0, bf2f((unsigned short)(z0 & 0xffff)), a0);
        a1 = fmaf(w0, bf2f((unsigned short)(z0 >> 16)), a1);
        a0 = fmaf(w1, bf2f((unsigned short)(z1 & 0xffff)), a0);
        a1 = fmaf(w1, bf2f((unsigned short)(z1 >> 16)), a1);
    }
    a0 += __shfl_xor(a0, 8, 64);  a1 += __shfl_xor(a1, 8, 64);
    a0 += __shfl_xor(a0, 16, 64); a1 += __shfl_xor(a1, 16, 64);
    a0 += __shfl_xor(a0, 32, 64); a1 += __shfl_xor(a1, 32, 64);

    const int j = lane & 15;
    float e0v = __shfl(a0, j >> 1, 64);
    float e1v = __shfl(a1, j >> 1, 64);
    float accj = (j & 1) ? e1v : e0v;

    float h2 = fmaxf(accj + b2[j], 0.f);
    float s3 = 0.f;
#pragma unroll
    for (int k = 0; k < G; ++k) s3 = fmaf(__shfl(h2, k, 64), WlS[k * G + j], s3);
    float h3 = fmaxf(s3 + bl[j], 0.f);
    float m = h3;
    m = fmaxf(m, __shfl_xor(m, 1, 64));
    m = fmaxf(m, __shfl_xor(m, 2, 64));
    m = fmaxf(m, __shfl_xor(m, 4, 64));
    m = fmaxf(m, __shfl_xor(m, 8, 64));
    float ex = __expf(h3 - m);
    float se = ex;
    se += __shfl_xor(se, 1, 64);
    se += __shfl_xor(se, 2, 64);
    se += __shfl_xor(se, 4, 64);
    se += __shfl_xor(se, 8, 64);
    float y = ex / se;
    if (lane < G) {
        Yb[n * G + j] = f2bf(y);
        atomicAdd(&gsh[j], y * Dv[n]);
    }
    __syncthreads();
    if (tid < G) atomicAdd(&GammaP[(blockIdx.x & 63) * G + tid], gsh[tid]);
}

// ---------------- Gamma finalize ----------------
__global__ void k_gfin(const float* __restrict__ GammaP, float* __restrict__ invG) {
    int j = threadIdx.x;
    if (j < G) {
        float s = 0.f;
        for (int b = 0; b < 64; ++b) s += GammaP[b * G + j];
        invG[j] = 1.0f / s;
    }
}

// ---------------- edge loss (CSR, wave per node, bf16 Y, slotted partials) ----------------
__global__ __launch_bounds__(256) void k_loss(const unsigned short* __restrict__ Yb, const int* __restrict__ rowptr,
                                              const int2* __restrict__ E, const float* __restrict__ invG,
                                              float* __restrict__ lossP) {
    __shared__ float pw[4];
    const int tid = threadIdx.x;
    const int lane = tid & 63;
    const int g = lane >> 3;
    const int d = lane & 7;
    const int n = blockIdx.x * 4 + (tid >> 6);
    const int s = __builtin_amdgcn_readfirstlane(rowptr[n]);
    const int e = __builtin_amdgcn_readfirstlane(rowptr[n + 1]);
    const char* Yc = (const char*)Yb;
    const i32x2* Ev = (const i32x2*)E;

    unsigned yr = *(const unsigned*)(Yc + ((size_t)n << 5) + d * 4);
    float yg0 = bf2f((unsigned short)(yr & 0xffff)) * invG[2 * d];
    float yg1 = bf2f((unsigned short)(yr >> 16))    * invG[2 * d + 1];

    float part = 0.f;
    for (int base = s; base < e; base += 16) {
        int i0 = base + g;
        int i1 = base + 8 + g;
        i32x2 e0 = __builtin_nontemporal_load(&Ev[(i0 < e) ? i0 : s]);
        i32x2 e1 = __builtin_nontemporal_load(&Ev[(i1 < e) ? i1 : s]);
        float w0 = (i0 < e) ? __int_as_float(e0.y) : 0.f;
        float w1 = (i1 < e) ? __int_as_float(e1.y) : 0.f;
        unsigned z0 = *(const unsigned*)(Yc + (e0.x >> 3) + d * 4);
        unsigned z1 = *(const unsigned*)(Yc + (e1.x >> 3) + d * 4);
        float t0 = yg0 * bf2f((unsigned short)(z0 & 0xffff)) + yg1 * bf2f((unsigned short)(z0 >> 16));
        float t1 = yg0 * bf2f((unsigned short)(z1 & 0xffff)) + yg1 * bf2f((unsigned short)(z1 >> 16));
        part = fmaf(w0, t0, part);
        part = fmaf(w1, t1, part);
    }
#pragma unroll
    for (int off = 1; off < 64; off <<= 1) part += __shfl_xor(part, off, 64);
    if (lane == 0) pw[tid >> 6] = part;
    __syncthreads();
    if (tid == 0) atomicAdd(&lossP[blockIdx.x & (LSLOTS - 1)], pw[0] + pw[1] + pw[2] + pw[3]);
}

__global__ void k_final(const float* __restrict__ lossP, float* __restrict__ out) {
    const int tid = threadIdx.x;
    float s = lossP[tid] + lossP[tid + 64] + lossP[tid + 128] + lossP[tid + 192];
#pragma unroll
    for (int off = 1; off < 64; off <<= 1) s += __shfl_xor(s, off, 64);
    if (tid == 0) out[0] = 16.0f - s;
}

// ---------------- launcher ----------------
static inline size_t alignup(size_t x) { return (x + 255) & ~(size_t)255; }

extern "C" void kernel_launch(void* const* d_in, const int* in_sizes, int n_in,
                              void* d_out, int out_size, void* d_ws, size_t ws_size,
                              hipStream_t stream) {
    const float* H  = (const float*)d_in[0];
    const int*   ei = (const int*)d_in[1];
    const float* ev = (const float*)d_in[2];
    const float* W1 = (const float*)d_in[3];
    const float* b1 = (const float*)d_in[4];
    const float* W2 = (const float*)d_in[5];
    const float* b2 = (const float*)d_in[6];
    const float* Wl = (const float*)d_in[7];
    const float* bl = (const float*)d_in[8];
    const int* row = ei;
    const int* col = ei + NE;

    char* base = (char*)d_ws;
    size_t off = 0;
    unsigned char*  XW  = (unsigned char*)(base + off);  off = alignup(off + (size_t)NN * F1);
    unsigned short* W1t = (unsigned short*)(base + off); off = alignup(off + (size_t)F0 * F1 * 2);
    unsigned short* Z   = (unsigned short*)(base + off); off = alignup(off + (size_t)NN * G * 2);
    unsigned short* Yb  = (unsigned short*)(base + off); off = alignup(off + (size_t)NN * G * 2);
    float* Dv     = (float*)(base + off); off = alignup(off + (size_t)NN * 4);
    float* GammaP = (float*)(base + off); off = alignup(off + (size_t)64 * G * 4);
    float* invG   = (float*)(base + off); off = alignup(off + (size_t)G * 4);
    float* lossP  = (float*)(base + off); off = alignup(off + (size_t)LSLOTS * 4);
    int*   rowptr = (int*)(base + off);   off = alignup(off + (size_t)(NN + 1) * 4);
    int*   ccur   = (int*)(base + off);   off = alignup(off + (size_t)CB * 4);
    int2*  cbuf   = (int2*)(base + off);  off = alignup(off + (size_t)CB * CCAP * 8);
    int2*  E      = (int2*)(base + off);  off = alignup(off + (size_t)NE * 8);

    hipMemsetAsync(ccur, 0, (size_t)CB * 4, stream);
    hipMemsetAsync(GammaP, 0, (size_t)64 * G * 4, stream);
    hipMemsetAsync(lossP, 0, (size_t)LSLOTS * 4, stream);

    k_passA<<<dim3((NE + CHUNK - 1) / CHUNK), dim3(256), 0, stream>>>(row, col, ev, ccur, cbuf);
    k_passB<<<dim3(CB), dim3(256), 0, stream>>>(cbuf, ccur, rowptr, E);
    k_castW1<<<dim3((F0 * F1 + 255) / 256), dim3(256), 0, stream>>>(W1, W1t);
    k_gemm1<<<dim3((NN + 127) / 128, F1 / 128), dim3(256), 0, stream>>>(H, W1t, XW);
    k_spmm1<<<dim3(NN / 4), dim3(256), 0, stream>>>(XW, rowptr, E, b1, W2, Z, Dv);
    k_head<<<dim3(NN / 4), dim3(256), 0, stream>>>(Z, rowptr, E, b2, Wl, bl, Dv, Yb, GammaP);
    k_gfin<<<dim3(1), dim3(64), 0, stream>>>(GammaP, invG);
    k_loss<<<dim3(NN / 4), dim3(256), 0, stream>>>(Yb, rowptr, E, invG, lossP);
    k_final<<<dim3(1), dim3(64), 0, stream>>>(lossP, (float*)d_out);
}

// Round 11
// 429.563 us; speedup vs baseline: 1.6484x; 1.0141x over previous
//
#include <hip/hip_runtime.h>

// GCN forward + NCut loss on MI355X.
// R11: fuse gemm1 ∪ passA into one dispatch (independent chains overlap on-chip);
//      loss accumulates per-j numerators S_j (no invG dependency, gfin removed,
//      division deferred to k_final); single fused memset. 12 -> 8 dispatches.
// loss = 16 - sum_j S_j/Gamma_j,  S_j = sum_e w_e Y[r,j] Y[c,j]

constexpr int NN = 50000;
constexpr int NE = 1600000;
constexpr int F0 = 512;
constexpr int F1 = 256;
constexpr int G  = 16;
constexpr int CB   = 196;      // coarse buckets: row>>8
constexpr int CCAP = 10240;    // capacity per coarse bucket (mean 8163)
constexpr int CHUNK = 4096;    // edges per passA block
constexpr int NGEMM = 391 * 2; // gemm tiles in fused kernel

typedef short  s16x8 __attribute__((ext_vector_type(8)));
typedef float  f32x4 __attribute__((ext_vector_type(4)));
typedef float  f32x2 __attribute__((ext_vector_type(2)));
typedef int    i32x4 __attribute__((ext_vector_type(4)));
typedef int    i32x2 __attribute__((ext_vector_type(2)));
typedef float  fv4   __attribute__((ext_vector_type(4)));

static __device__ __forceinline__ unsigned short f2bf(float f) {
    union { float f; unsigned u; } v; v.f = f;
    unsigned r = (v.u + 0x7FFFu + ((v.u >> 16) & 1u)) >> 16;   // RNE
    return (unsigned short)r;
}
static __device__ __forceinline__ float bf2f(unsigned short u) {
    union { unsigned u; float f; } v; v.u = (unsigned)u << 16;
    return v.f;
}

// ---------------- W1 pre-cast+transpose ----------------
__global__ __launch_bounds__(256) void k_castW1(const float* __restrict__ W1, unsigned short* __restrict__ W1t) {
    int idx = blockIdx.x * 256 + threadIdx.x;
    if (idx < F0 * F1) {
        int k = idx >> 8, n = idx & 255;
        W1t[n * F0 + k] = f2bf(W1[idx]);
    }
}

// ---------------- fused: GEMM1 (bf16 MFMA -> fp8 XW)  ∪  passA (coarse scatter) ----------------
__global__ __launch_bounds__(256) void k_fused1(const float* __restrict__ H,
                                                const unsigned short* __restrict__ W1t,
                                                unsigned char* __restrict__ XW,
                                                const int* __restrict__ row, const int* __restrict__ col,
                                                const float* __restrict__ ev,
                                                int* __restrict__ ccur, int2* __restrict__ cbuf) {
    __shared__ __align__(16) unsigned char smem[2 * 128 * 72 * 2];   // 36864 B
    const int bid = blockIdx.x;
    const int tid = threadIdx.x;

    if (bid < NGEMM) {
        // ================= GEMM1 tile =================
        unsigned short (*As)[72] = (unsigned short(*)[72])smem;
        unsigned short (*Bs)[72] = (unsigned short(*)[72])(smem + 128 * 72 * 2);
        const int lane = tid & 63;
        const int wave = tid >> 6;
        const int bm = (bid >> 1) * 128;
        const int bn = (bid & 1) * 128;
        const int m_off = (wave & 1) * 64;
        const int n_off = (wave >> 1) * 64;
        const int l15  = lane & 15;
        const int quad = lane >> 4;

        f32x4 acc[4][4];
#pragma unroll
        for (int i = 0; i < 4; ++i)
#pragma unroll
            for (int j = 0; j < 4; ++j) acc[i][j] = (f32x4)0.f;

        const int arow = tid >> 4;
        const int akq  = tid & 15;
        const int brow = tid >> 3;
        const int bkq  = tid & 7;

        for (int k0 = 0; k0 < F0; k0 += 64) {
            __syncthreads();
#pragma unroll
            for (int p = 0; p < 8; ++p) {
                int r = p * 16 + arow;
                int gr = bm + r;
                float4 a4 = make_float4(0.f, 0.f, 0.f, 0.f);
                if (gr < NN) a4 = *(const float4*)&H[(size_t)gr * F0 + k0 + akq * 4];
                unsigned short* dst = &As[r][akq * 4];
                dst[0] = f2bf(a4.x); dst[1] = f2bf(a4.y); dst[2] = f2bf(a4.z); dst[3] = f2bf(a4.w);
            }
#pragma unroll
            for (int p = 0; p < 4; ++p) {
                int n = p * 32 + brow;
                uint4 b8 = *(const uint4*)&W1t[(bn + n) * F0 + k0 + bkq * 8];
                *(uint4*)&Bs[n][bkq * 8] = b8;
            }
            __syncthreads();
#pragma unroll
            for (int kk = 0; kk < 64; kk += 32) {
                s16x8 af[4], bfr[4];
#pragma unroll
                for (int mi = 0; mi < 4; ++mi)
                    af[mi] = *(const s16x8*)&As[m_off + mi * 16 + l15][kk + quad * 8];
#pragma unroll
                for (int ni = 0; ni < 4; ++ni)
                    bfr[ni] = *(const s16x8*)&Bs[n_off + ni * 16 + l15][kk + quad * 8];
#pragma unroll
                for (int mi = 0; mi < 4; ++mi)
#pragma unroll
                    for (int ni = 0; ni < 4; ++ni)
                        acc[mi][ni] = __builtin_amdgcn_mfma_f32_16x16x32_bf16(af[mi], bfr[ni], acc[mi][ni], 0, 0, 0);
            }
        }
#pragma unroll
        for (int mi = 0; mi < 4; ++mi) {
            int r0 = bm + m_off + mi * 16 + quad * 4;
#pragma unroll
            for (int reg = 0; reg < 4; ++reg) {
                int gr = r0 + reg;
                if (gr < NN) {
                    unsigned char* orow = &XW[(size_t)gr * F1 + bn + n_off];
#pragma unroll
                    for (int ni = 0; ni < 4; ++ni) {
                        int pk = __builtin_amdgcn_cvt_pk_fp8_f32(acc[mi][ni][reg], 0.f, 0, false);
                        orow[ni * 16 + l15] = (unsigned char)(pk & 0xff);
                    }
                }
            }
        }
    } else {
        // ================= passA chunk =================
        int* hcnt  = (int*)smem;
        int* hbase = hcnt + CB;
        for (int i = tid; i < CB; i += 256) hcnt[i] = 0;
        __syncthreads();

        const int base4 = (bid - NGEMM) * (CHUNK / 4);   // int4 units
        int recx[16]; float recw[16]; int cb[16];
#pragma unroll
        for (int k = 0; k < 4; ++k) {
            int i4 = base4 + k * 256 + tid;
            bool ok = i4 < NE / 4;
            i32x4 r = ok ? __builtin_nontemporal_load(&((const i32x4*)row)[i4]) : (i32x4)0;
            i32x4 c = ok ? __builtin_nontemporal_load(&((const i32x4*)col)[i4]) : (i32x4)0;
            fv4   w = ok ? __builtin_nontemporal_load(&((const fv4*)ev)[i4])   : (fv4)0.f;
            int rr[4] = {r.x, r.y, r.z, r.w};
            int cc[4] = {c.x, c.y, c.z, c.w};
            float ww[4] = {w.x, w.y, w.z, w.w};
#pragma unroll
            for (int j = 0; j < 4; ++j) {
                int slot = k * 4 + j;
                if (ok) {
                    cb[slot] = rr[j] >> 8;
                    atomicAdd(&hcnt[cb[slot]], 1);
                } else {
                    cb[slot] = -1;
                }
                recx[slot] = (cc[j] << 16) | (rr[j] & 255);
                recw[slot] = ww[j];
            }
        }
        __syncthreads();
        for (int i = tid; i < CB; i += 256) {
            int cnt = hcnt[i];
            hbase[i] = (cnt > 0) ? atomicAdd(&ccur[i], cnt) : 0;
            hcnt[i] = 0;                                   // reuse as local cursor
        }
        __syncthreads();
#pragma unroll
        for (int slot = 0; slot < 16; ++slot) {
            if (cb[slot] >= 0) {
                int p = hbase[cb[slot]] + atomicAdd(&hcnt[cb[slot]], 1);
                cbuf[(size_t)cb[slot] * CCAP + p] = make_int2(recx[slot], __float_as_int(recw[slot]));
            }
        }
    }
}

// ---------------- passB: build rowptr slice + fine scatter ----------------
__global__ __launch_bounds__(256) void k_passB(const int2* __restrict__ cbuf, const int* __restrict__ ccur,
                                               int* __restrict__ rowptr, int2* __restrict__ E) {
    __shared__ int cnt[256];
    __shared__ int scn[256];
    __shared__ int red[4];
    const int cbk = blockIdx.x;     // 0..195
    const int tid = threadIdx.x;
    cnt[tid] = 0;

    // base = sum(ccur[0..cbk))
    int b = 0;
    for (int i = tid; i < cbk; i += 256) b += ccur[i];
#pragma unroll
    for (int off = 1; off < 64; off <<= 1) b += __shfl_xor(b, off, 64);
    if ((tid & 63) == 0) red[tid >> 6] = b;
    __syncthreads();
    const int base = red[0] + red[1] + red[2] + red[3];

    const int total = ccur[cbk];
    const int2* src = cbuf + (size_t)cbk * CCAP;
    for (int i = tid; i < total; i += 256) atomicAdd(&cnt[src[i].x & 255], 1);
    __syncthreads();

    scn[tid] = cnt[tid];
    __syncthreads();
    for (int off = 1; off < 256; off <<= 1) {
        int t = (tid >= off) ? scn[tid - off] : 0;
        __syncthreads();
        scn[tid] += t;
        __syncthreads();
    }
    const int excl = scn[tid] - cnt[tid];
    const int r = (cbk << 8) + tid;
    if (r <= NN) rowptr[r] = base + excl;   // block 195 covers rowptr[NN]=NE
    __syncthreads();
    cnt[tid] = base + excl;                 // reuse as cursor
    __syncthreads();
    for (int i = tid; i < total; i += 256) {
        int2 rec = src[i];
        int rl = rec.x & 255;
        int c  = (int)((unsigned)rec.x >> 16);
        int p = atomicAdd(&cnt[rl], 1);
        E[p] = make_int2(c << 8, rec.y);
    }
}

// ---------------- SPMM1 + bias + relu + fused GEMM2 (fp8 gather) ----------------
__global__ __launch_bounds__(256) void k_spmm1(const unsigned char* __restrict__ XW, const int* __restrict__ rowptr,
                                               const int2* __restrict__ E,
                                               const float* __restrict__ b1, const float* __restrict__ W2,
                                               unsigned short* __restrict__ Z, float* __restrict__ Dv) {
    __shared__ float W2T[G * F1];
    const int tid = threadIdx.x;
#pragma unroll
    for (int it = 0; it < 16; ++it)
        W2T[it * 256 + tid] = W2[tid * 16 + it];   // conflict-free writes
    __syncthreads();
    const int lane = tid & 63;
    const int lane4 = lane * 4;
    const int n = blockIdx.x * 4 + (tid >> 6);
    const int s = __builtin_amdgcn_readfirstlane(rowptr[n]);
    const int e = __builtin_amdgcn_readfirstlane(rowptr[n + 1]);
    const i32x2* Ev = (const i32x2*)E;

    float4 acc = make_float4(0.f, 0.f, 0.f, 0.f);
    float wsum = 0.f;
    int i = s;
    for (; i + 8 <= e; i += 8) {
        int of[8]; float w[8];
#pragma unroll
        for (int k = 0; k < 8; ++k) {
            i32x2 ed = __builtin_nontemporal_load(&Ev[i + k]);
            of[k] = ed.x; w[k] = __int_as_float(ed.y);
        }
        unsigned gg[8];
#pragma unroll
        for (int k = 0; k < 8; ++k) gg[k] = *(const unsigned*)(XW + of[k] + lane4);
#pragma unroll
        for (int k = 0; k < 8; ++k) {
            f32x2 lo = __builtin_amdgcn_cvt_pk_f32_fp8(gg[k], false);
            f32x2 hi = __builtin_amdgcn_cvt_pk_f32_fp8(gg[k], true);
            acc.x = fmaf(w[k], lo.x, acc.x); acc.y = fmaf(w[k], lo.y, acc.y);
            acc.z = fmaf(w[k], hi.x, acc.z); acc.w = fmaf(w[k], hi.y, acc.w);
            wsum += w[k];
        }
    }
    for (; i < e; i += 4) {
        int of[4]; float w[4];
#pragma unroll
        for (int k = 0; k < 4; ++k) {
            int idx = i + k;
            bool ok = idx < e;
            i32x2 ed = Ev[ok ? idx : s];
            of[k] = ed.x; w[k] = ok ? __int_as_float(ed.y) : 0.f;
        }
        unsigned gg[4];
#pragma unroll
        for (int k = 0; k < 4; ++k) gg[k] = *(const unsigned*)(XW + of[k] + lane4);
#pragma unroll
        for (int k = 0; k < 4; ++k) {
            f32x2 lo = __builtin_amdgcn_cvt_pk_f32_fp8(gg[k], false);
            f32x2 hi = __builtin_amdgcn_cvt_pk_f32_fp8(gg[k], true);
            acc.x = fmaf(w[k], lo.x, acc.x); acc.y = fmaf(w[k], lo.y, acc.y);
            acc.z = fmaf(w[k], hi.x, acc.z); acc.w = fmaf(w[k], hi.y, acc.w);
            wsum += w[k];
        }
    }
    if (lane == 0) Dv[n] = wsum;

    float4 bb = *(const float4*)&b1[lane * 4];
    float4 h;
    h.x = fmaxf(acc.x + bb.x, 0.f);
    h.y = fmaxf(acc.y + bb.y, 0.f);
    h.z = fmaxf(acc.z + bb.z, 0.f);
    h.w = fmaxf(acc.w + bb.w, 0.f);

    float p[G];
#pragma unroll
    for (int j = 0; j < G; ++j) {
        float4 w4 = *(const float4*)&W2T[j * F1 + lane * 4];
        p[j] = h.x * w4.x + h.y * w4.y + h.z * w4.z + h.w * w4.w;
    }
#pragma unroll
    for (int off = 1; off < 64; off <<= 1) {
#pragma unroll
        for (int j = 0; j < G; ++j) p[j] += __shfl_xor(p[j], off, 64);
    }
    if (lane == 0) {
        unsigned zp[8];
#pragma unroll
        for (int j = 0; j < 8; ++j)
            zp[j] = (unsigned)f2bf(p[2 * j]) | ((unsigned)f2bf(p[2 * j + 1]) << 16);
        uint4* zo = (uint4*)&Z[n * G];
        zo[0] = make_uint4(zp[0], zp[1], zp[2], zp[3]);
        zo[1] = make_uint4(zp[4], zp[5], zp[6], zp[7]);
    }
}

// ---------------- SPMM2 + head + softmax + Gamma ----------------
__global__ __launch_bounds__(256) void k_head(const unsigned short* __restrict__ Zb, const int* __restrict__ rowptr,
                                              const int2* __restrict__ E,
                                              const float* __restrict__ b2, const float* __restrict__ Wl,
                                              const float* __restrict__ bl, const float* __restrict__ Dv,
                                              unsigned short* __restrict__ Yb, float* __restrict__ GammaP) {
    __shared__ float WlS[G * G];
    __shared__ float gsh[G];
    const int tid = threadIdx.x;
    if (tid < G * G) WlS[tid] = Wl[tid];
    if (tid < G) gsh[tid] = 0.f;
    __syncthreads();
    const int lane = tid & 63;
    const int g = lane >> 3;      // edge slot 0..7
    const int d = lane & 7;       // dword in Z row
    const int n = blockIdx.x * 4 + (tid >> 6);
    const int s = __builtin_amdgcn_readfirstlane(rowptr[n]);
    const int e = __builtin_amdgcn_readfirstlane(rowptr[n + 1]);
    const char* Zc = (const char*)Zb;
    const i32x2* Ev = (const i32x2*)E;

    float a0 = 0.f, a1 = 0.f;
    for (int base = s; base < e; base += 16) {
        int i0 = base + g;
        int i1 = base + 8 + g;
        i32x2 e0 = __builtin_nontemporal_load(&Ev[(i0 < e) ? i0 : s]);
        i32x2 e1 = __builtin_nontemporal_load(&Ev[(i1 < e) ? i1 : s]);
        float w0 = (i0 < e) ? __int_as_float(e0.y) : 0.f;
        float w1 = (i1 < e) ? __int_as_float(e1.y) : 0.f;
        unsigned z0 = *(const unsigned*)(Zc + (e0.x >> 3) + d * 4);
        unsigned z1 = *(const unsigned*)(Zc + (e1.x >> 3) + d * 4);
        a0 = fmaf(w0, bf2f((unsigned short)(z0 & 0xffff)), a0);
        a1 = fmaf(w0, bf2f((unsigned short)(z0 >> 16)), a1);
        a0 = fmaf(w1, bf2f((unsigned short)(z1 & 0xffff)), a0);
        a1 = fmaf(w1, bf2f((unsigned short)(z1 >> 16)), a1);
    }
    a0 += __shfl_xor(a0, 8, 64);  a1 += __shfl_xor(a1, 8, 64);
    a0 += __shfl_xor(a0, 16, 64); a1 += __shfl_xor(a1, 16, 64);
    a0 += __shfl_xor(a0, 32, 64); a1 += __shfl_xor(a1, 32, 64);

    const int j = lane & 15;
    float e0v = __shfl(a0, j >> 1, 64);
    float e1v = __shfl(a1, j >> 1, 64);
    float accj = (j & 1) ? e1v : e0v;

    float h2 = fmaxf(accj + b2[j], 0.f);
    float s3 = 0.f;
#pragma unroll
    for (int k = 0; k < G; ++k) s3 = fmaf(__shfl(h2, k, 64), WlS[k * G + j], s3);
    float h3 = fmaxf(s3 + bl[j], 0.f);
    float m = h3;
    m = fmaxf(m, __shfl_xor(m, 1, 64));
    m = fmaxf(m, __shfl_xor(m, 2, 64));
    m = fmaxf(m, __shfl_xor(m, 4, 64));
    m = fmaxf(m, __shfl_xor(m, 8, 64));
    float ex = __expf(h3 - m);
    float se = ex;
    se += __shfl_xor(se, 1, 64);
    se += __shfl_xor(se, 2, 64);
    se += __shfl_xor(se, 4, 64);
    se += __shfl_xor(se, 8, 64);
    float y = ex / se;
    if (lane < G) {
        Yb[n * G + j] = f2bf(y);
        atomicAdd(&gsh[j], y * Dv[n]);
    }
    __syncthreads();
    if (tid < G) atomicAdd(&GammaP[(blockIdx.x & 63) * G + tid], gsh[tid]);
}

// ---------------- edge loss numerators: S_j = sum_e w Y[r,j]Y[c,j] (slotted) ----------------
__global__ __launch_bounds__(256) void k_loss(const unsigned short* __restrict__ Yb, const int* __restrict__ rowptr,
                                              const int2* __restrict__ E, float* __restrict__ SjP) {
    __shared__ float sjsh[G];
    const int tid = threadIdx.x;
    if (tid < G) sjsh[tid] = 0.f;
    __syncthreads();
    const int lane = tid & 63;
    const int g = lane >> 3;
    const int d = lane & 7;
    const int n = blockIdx.x * 4 + (tid >> 6);
    const int s = __builtin_amdgcn_readfirstlane(rowptr[n]);
    const int e = __builtin_amdgcn_readfirstlane(rowptr[n + 1]);
    const char* Yc = (const char*)Yb;
    const i32x2* Ev = (const i32x2*)E;

    unsigned yr = *(const unsigned*)(Yc + ((size_t)n << 5) + d * 4);
    float y0 = bf2f((unsigned short)(yr & 0xffff));
    float y1 = bf2f((unsigned short)(yr >> 16));

    float s0 = 0.f, s1 = 0.f;
    for (int base = s; base < e; base += 16) {
        int i0 = base + g;
        int i1 = base + 8 + g;
        i32x2 e0 = __builtin_nontemporal_load(&Ev[(i0 < e) ? i0 : s]);
        i32x2 e1 = __builtin_nontemporal_load(&Ev[(i1 < e) ? i1 : s]);
        float w0 = (i0 < e) ? __int_as_float(e0.y) : 0.f;
        float w1 = (i1 < e) ? __int_as_float(e1.y) : 0.f;
        unsigned z0 = *(const unsigned*)(Yc + (e0.x >> 3) + d * 4);
        unsigned z1 = *(const unsigned*)(Yc + (e1.x >> 3) + d * 4);
        s0 = fmaf(w0 * y0, bf2f((unsigned short)(z0 & 0xffff)), s0);
        s1 = fmaf(w0 * y1, bf2f((unsigned short)(z0 >> 16)), s1);
        s0 = fmaf(w1 * y0, bf2f((unsigned short)(z1 & 0xffff)), s0);
        s1 = fmaf(w1 * y1, bf2f((unsigned short)(z1 >> 16)), s1);
    }
    // sum over the 8 edge-slot groups (bits 3..5 of lane)
    s0 += __shfl_xor(s0, 8, 64);  s1 += __shfl_xor(s1, 8, 64);
    s0 += __shfl_xor(s0, 16, 64); s1 += __shfl_xor(s1, 16, 64);
    s0 += __shfl_xor(s0, 32, 64); s1 += __shfl_xor(s1, 32, 64);
    if (lane < 8) {
        atomicAdd(&sjsh[2 * lane],     s0);
        atomicAdd(&sjsh[2 * lane + 1], s1);
    }
    __syncthreads();
    if (tid < G) atomicAdd(&SjP[(blockIdx.x & 63) * G + tid], sjsh[tid]);
}

// ---------------- finalize: loss = 16 - sum_j S_j / Gamma_j ----------------
__global__ void k_final(const float* __restrict__ GammaP, const float* __restrict__ SjP,
                        float* __restrict__ out) {
    const int tid = threadIdx.x;   // 64 threads, j = tid&15 (dup groups harmless)
    const int j = tid & 15;
    float gam = 0.f, sj = 0.f;
    for (int b = 0; b < 64; ++b) {
        gam += GammaP[b * G + j];
        sj  += SjP[b * G + j];
    }
    float v = sj / gam;
    v += __shfl_xor(v, 1, 64);
    v += __shfl_xor(v, 2, 64);
    v += __shfl_xor(v, 4, 64);
    v += __shfl_xor(v, 8, 64);
    if (tid == 0) out[0] = 16.0f - v;
}

// ---------------- launcher ----------------
static inline size_t alignup(size_t x) { return (x + 255) & ~(size_t)255; }

extern "C" void kernel_launch(void* const* d_in, const int* in_sizes, int n_in,
                              void* d_out, int out_size, void* d_ws, size_t ws_size,
                              hipStream_t stream) {
    const float* H  = (const float*)d_in[0];
    const int*   ei = (const int*)d_in[1];
    const float* ev = (const float*)d_in[2];
    const float* W1 = (const float*)d_in[3];
    const float* b1 = (const float*)d_in[4];
    const float* W2 = (const float*)d_in[5];
    const float* b2 = (const float*)d_in[6];
    const float* Wl = (const float*)d_in[7];
    const float* bl = (const float*)d_in[8];
    const int* row = ei;
    const int* col = ei + NE;

    char* base = (char*)d_ws;
    size_t off = 0;
    unsigned char*  XW  = (unsigned char*)(base + off);  off = alignup(off + (size_t)NN * F1);
    unsigned short* W1t = (unsigned short*)(base + off); off = alignup(off + (size_t)F0 * F1 * 2);
    unsigned short* Z   = (unsigned short*)(base + off); off = alignup(off + (size_t)NN * G * 2);
    unsigned short* Yb  = (unsigned short*)(base + off); off = alignup(off + (size_t)NN * G * 2);
    float* Dv     = (float*)(base + off); off = alignup(off + (size_t)NN * 4);
    // zeroed region: ccur | GammaP | SjP (one memset)
    size_t zoff = off;
    int*   ccur   = (int*)(base + off);   off += (size_t)CB * 4;
    float* GammaP = (float*)(base + off); off += (size_t)64 * G * 4;
    float* SjP    = (float*)(base + off); off += (size_t)64 * G * 4;
    size_t zsize = off - zoff;
    off = alignup(off);
    int*   rowptr = (int*)(base + off);   off = alignup(off + (size_t)(NN + 1) * 4);
    int2*  cbuf   = (int2*)(base + off);  off = alignup(off + (size_t)CB * CCAP * 8);
    int2*  E      = (int2*)(base + off);  off = alignup(off + (size_t)NE * 8);

    hipMemsetAsync(base + zoff, 0, zsize, stream);

    k_castW1<<<dim3((F0 * F1 + 255) / 256), dim3(256), 0, stream>>>(W1, W1t);
    k_fused1<<<dim3(NGEMM + (NE + CHUNK - 1) / CHUNK), dim3(256), 0, stream>>>(
        H, W1t, XW, row, col, ev, ccur, cbuf);
    k_passB<<<dim3(CB), dim3(256), 0, stream>>>(cbuf, ccur, rowptr, E);
    k_spmm1<<<dim3(NN / 4), dim3(256), 0, stream>>>(XW, rowptr, E, b1, W2, Z, Dv);
    k_head<<<dim3(NN / 4), dim3(256), 0, stream>>>(Z, rowptr, E, b2, Wl, bl, Dv, Yb, GammaP);
    k_loss<<<dim3(NN / 4), dim3(256), 0, stream>>>(Yb, rowptr, E, SjP);
    k_final<<<dim3(1), dim3(64), 0, stream>>>(GammaP, SjP, (float*)d_out);
}